// Round 8
// baseline (276.472 us; speedup 1.0000x reference)
//
#include <hip/hip_runtime.h>
#include <hip/hip_fp16.h>
#include <cstdint>
#include <cstddef>

// Problem constants: B=256, C=1, NMAX=256 -> N=65536 nodes, E=N*16=1048576,
// EMB=HID=128, decode K = NMAX = 256.
#define NN   65536
#define NE   1048576
#define FD   128
#define KDEC 256
#define NGRAPH 256
// padded edge capacity: sum ceil(cnt/16)*16 <= NE + 15*NN
#define NEP_MAX (NE + 15 * NN)   // 2031616 records
#define DUMMY_SRC 65536u         // zero row index

typedef __attribute__((ext_vector_type(8))) short s16x8;
typedef __attribute__((ext_vector_type(4))) float f32x4;

__device__ __forceinline__ ushort f2bf(float x) {
  uint u = __float_as_uint(x);
  uint r = (u + 0x7fffu + ((u >> 16) & 1u)) >> 16;  // RNE
  return (ushort)r;
}
__device__ __forceinline__ float bf2f(ushort h) {
  return __uint_as_float(((uint)h) << 16);
}

// ---------------- CSR build ----------------

// blocks 0..4095: dst histogram. blocks 4096..6079: fill ec with dummy records.
__global__ __launch_bounds__(256) void k_hist(const int* __restrict__ edges,
                                              int* __restrict__ hist,
                                              uint* __restrict__ ec) {
  int b = blockIdx.x, t = threadIdx.x;
  if (b < NE / 256) {
    int i = b * 256 + t;
    atomicAdd(&hist[edges[2 * i + 1]], 1);
  } else {
    int fi = (b - NE / 256) * 1024 + t * 4;  // 1984 blocks * 1024 = NEP_MAX
    *(uint4*)(ec + fi) = make_uint4(DUMMY_SRC, DUMMY_SRC, DUMMY_SRC, DUMMY_SRC);
  }
}

// W pre-fragmentation helper (split bf16, fragment-major):
// dst(k,c) = ((k/32)*8 + c/16)*512 + ((c&15) + 16*((k&31)>>3))*8 + (k&7)
__device__ __forceinline__ void prep_one(const float* __restrict__ W,
                                         ushort* __restrict__ H,
                                         ushort* __restrict__ L, int i) {
  int k = i >> 7, c = i & 127;
  float w = W[i];
  ushort h = f2bf(w);
  ushort lo = f2bf(w - bf2f(h));
  size_t dst = ((size_t)((k >> 5) * 8 + (c >> 4)) * 64 +
                (size_t)((c & 15) + 16 * ((k & 31) >> 3))) * 8 + (k & 7);
  H[dst] = h;
  L[dst] = lo;
}

// misc1: blocks 0-255 blocksum over PADDED counts | 256-383 Wfused (+bfused) |
//        384-447 prep Wc2
__global__ __launch_bounds__(256) void k_misc1(const int* __restrict__ hist,
                                               int* __restrict__ bsum,
                                               const float* __restrict__ Wdec,
                                               const float* __restrict__ Wc1,
                                               const float* __restrict__ bdec,
                                               float* __restrict__ wfused,
                                               float* __restrict__ bfused,
                                               const float* __restrict__ Wc2,
                                               ushort* __restrict__ w2h,
                                               ushort* __restrict__ w2l) {
  int b = blockIdx.x, t = threadIdx.x;
  if (b < 256) {
    __shared__ int s[256];
    s[t] = (hist[b * 256 + t] + 15) & ~15;  // padded
    __syncthreads();
    for (int st = 128; st > 0; st >>= 1) {
      if (t < st) s[t] += s[t + st];
      __syncthreads();
    }
    if (t == 0) bsum[b] = s[0];
  } else if (b < 384) {
    int i = (b - 256) * 256 + t;  // 0..32767
    int k = i >> 7, c = i & 127;
    float acc = 0.f;
#pragma unroll 8
    for (int j = 0; j < 128; j++) acc = fmaf(Wdec[k * FD + j], Wc1[j * FD + c], acc);
    wfused[i] = acc;
    if (b == 256 && t < 128) {
      float ba = 0.f;
      for (int j = 0; j < 128; j++) ba = fmaf(bdec[j], Wc1[j * FD + t], ba);
      bfused[t] = ba;
    }
  } else {
    int i = (b - 384) * 256 + t;  // 0..16383
    prep_one(Wc2, w2h, w2l, i);
  }
}

// misc2: blocks 0-255 scanfinal over PADDED counts (scanb fused) + dinv(real) |
//        256-383 prep Wfused
__global__ __launch_bounds__(256) void k_misc2(const int* __restrict__ hist,
                                               const int* __restrict__ bsum,
                                               int* __restrict__ offs,
                                               float* __restrict__ dinv,
                                               const float* __restrict__ wfused,
                                               ushort* __restrict__ wfh,
                                               ushort* __restrict__ wfl) {
  int b = blockIdx.x, t = threadIdx.x;
  if (b < 256) {
    __shared__ int sb[256];
    __shared__ int s[256];
    sb[t] = bsum[t];
    int v = hist[b * 256 + t];
    int vp = (v + 15) & ~15;
    s[t] = vp;
    __syncthreads();
    for (int off = 1; off < 256; off <<= 1) {
      int addb = (t >= off) ? sb[t - off] : 0;
      int add = (t >= off) ? s[t - off] : 0;
      __syncthreads();
      sb[t] += addb;
      s[t] += add;
      __syncthreads();
    }
    int pb = (b > 0) ? sb[b - 1] : 0;
    offs[b * 256 + t] = pb + s[t] - vp;  // padded exclusive offsets
    dinv[b * 256 + t] = rsqrtf((float)(v + 1));
  } else {
    int i = (b - 256) * 256 + t;  // 0..32767
    prep_one(wfused, wfh, wfl, i);
  }
}

// scatter: real edges dropped over the dummy fill; 4 B dword stores
__global__ __launch_bounds__(256) void k_scatter(const int* __restrict__ edges,
                                                 const int* __restrict__ offs,
                                                 int* __restrict__ cnt,
                                                 uint* __restrict__ ec) {
  int i = blockIdx.x * 256 + threadIdx.x;
  if (i < NE) {
    int s = edges[2 * i];
    int d = edges[2 * i + 1];
    int pos = offs[d] + atomicAdd(&cnt[d], 1);
    ec[pos] = (uint)s;
  }
}

// ---------------- split-bf16 MFMA GEMM: Y[M,128] = X[M,K] @ W[K,128] (+bias) ----
// BM=64: 256 threads = 4 waves, wave = one 16-row m-frag. ASPLIT: A pre-split
// bf16 planes; else fp32 A. Output row-major bf16, row-scaled by scale[] if set
// (pre-scaled gather table t = dinv*h).

template <bool ASPLIT>
__global__ __launch_bounds__(256) void k_gemm(const void* __restrict__ A0,
                                              const void* __restrict__ A1,
                                              const ushort* __restrict__ Whi,
                                              const ushort* __restrict__ Wlo,
                                              const float* __restrict__ bias,
                                              const float* __restrict__ scale,
                                              ushort* __restrict__ Y, int K) {
  const int t = threadIdx.x;
  const int w = t >> 6;
  const int l = t & 63;
  const int lr = l & 15;   // row-in-frag (A) / col-in-frag (B,C)
  const int kg = l >> 4;   // k-group 0..3
  const int r0 = blockIdx.x * 64 + w * 16;

  f32x4 acc[8];
#pragma unroll
  for (int nb = 0; nb < 8; nb++) acc[nb] = (f32x4)0.f;

  for (int ks = 0; ks < K; ks += 32) {
    s16x8 ah, al;
    if (ASPLIT) {
      size_t base = (size_t)(r0 + lr) * K + ks + kg * 8;
      ah = *(const s16x8*)((const ushort*)A0 + base);
      al = *(const s16x8*)((const ushort*)A1 + base);
    } else {
      const float* xp = (const float*)A0 + (size_t)(r0 + lr) * K + ks + kg * 8;
      f32x4 x0 = *(const f32x4*)xp;
      f32x4 x1 = *(const f32x4*)(xp + 4);
      float xv[8] = {x0.x, x0.y, x0.z, x0.w, x1.x, x1.y, x1.z, x1.w};
      union { ushort u[8]; s16x8 v; } H, L;
#pragma unroll
      for (int e = 0; e < 8; e++) {
        ushort h = f2bf(xv[e]);
        H.u[e] = h;
        L.u[e] = f2bf(xv[e] - bf2f(h));
      }
      ah = H.v;
      al = L.v;
    }
    const size_t bbase = (size_t)(ks >> 5) * 4096 + (size_t)l * 8;
#pragma unroll
    for (int nb = 0; nb < 8; nb++) {
      s16x8 bh = *(const s16x8*)(Whi + bbase + nb * 512);
      s16x8 bl = *(const s16x8*)(Wlo + bbase + nb * 512);
      acc[nb] = __builtin_amdgcn_mfma_f32_16x16x32_bf16(ah, bh, acc[nb], 0, 0, 0);
      acc[nb] = __builtin_amdgcn_mfma_f32_16x16x32_bf16(ah, bl, acc[nb], 0, 0, 0);
      acc[nb] = __builtin_amdgcn_mfma_f32_16x16x32_bf16(al, bh, acc[nb], 0, 0, 0);
    }
  }

  // epilogue: C/D col = lr (within frag), row = kg*4 + reg
  float dvr[4];
#pragma unroll
  for (int r = 0; r < 4; r++)
    dvr[r] = scale ? scale[r0 + kg * 4 + r] : 1.f;

#pragma unroll
  for (int nb = 0; nb < 8; nb++) {
    int col = nb * 16 + lr;
    float bv = bias ? bias[col] : 0.f;
#pragma unroll
    for (int r = 0; r < 4; r++) {
      size_t row = (size_t)(r0 + kg * 4 + r);
      Y[row * FD + col] = f2bf((acc[nb][r] + bv) * dvr[r]);
    }
  }
}

// ---------------- GCN aggregation: wave-per-node, UNIFORM 8-deep pipeline ------
// Table t = dinv*h, bf16 [NN+1][128] (row NN = zeros, dummy-pad target).
// Wave = 1 node; lane l: edge parity half=l>>5, dims dl=(l&31)*4 (ushort4).
// Segments padded to multiples of 16 -> single uniform loop, 8 gathers in
// flight per lane-half for EVERY node, zero remainder/divergence.
// out[d] = relu( dinv[d]*(sum_e t[src_e] + t[d]) + b )
// EMIT=0: write hi/lo bf16 planes. EMIT=1: fused segment-max pooling.

template <int EMIT>
__global__ __launch_bounds__(256) void k_agg(const ushort* __restrict__ h16,
                                             const uint* __restrict__ ec,
                                             const int* __restrict__ offs,
                                             const int* __restrict__ hist,
                                             const float* __restrict__ dinv,
                                             const float* __restrict__ bias,
                                             ushort* __restrict__ yhi,
                                             ushort* __restrict__ ylo,
                                             float* __restrict__ pooled) {
  __shared__ int pmax[128];
  const int t = threadIdx.x;
  if (EMIT == 1) {
    if (t < 128) pmax[t] = 0;
    __syncthreads();
  }
  const int n = blockIdx.x * 4 + (t >> 6);
  const int l = t & 63;
  const int half = l >> 5;
  const int dl = (l & 31) * 4;

  const int cnt_p = (hist[n] + 15) & ~15;  // padded count
  const uint* ep = ec + offs[n];

  float a0 = 0.f, a1 = 0.f, a2 = 0.f, a3 = 0.f;
  float b0 = 0.f, b1 = 0.f, b2 = 0.f, b3 = 0.f;
  for (int i = half; i < cnt_p; i += 16) {
    uint s0 = ep[i];
    uint s1 = ep[i + 2];
    uint s2 = ep[i + 4];
    uint s3 = ep[i + 6];
    uint s4 = ep[i + 8];
    uint s5 = ep[i + 10];
    uint s6 = ep[i + 12];
    uint s7 = ep[i + 14];
    ushort4 v0 = *(const ushort4*)(h16 + ((size_t)s0 << 7) + dl);
    ushort4 v1 = *(const ushort4*)(h16 + ((size_t)s1 << 7) + dl);
    ushort4 v2 = *(const ushort4*)(h16 + ((size_t)s2 << 7) + dl);
    ushort4 v3 = *(const ushort4*)(h16 + ((size_t)s3 << 7) + dl);
    ushort4 v4 = *(const ushort4*)(h16 + ((size_t)s4 << 7) + dl);
    ushort4 v5 = *(const ushort4*)(h16 + ((size_t)s5 << 7) + dl);
    ushort4 v6 = *(const ushort4*)(h16 + ((size_t)s6 << 7) + dl);
    ushort4 v7 = *(const ushort4*)(h16 + ((size_t)s7 << 7) + dl);
    a0 += bf2f(v0.x); a1 += bf2f(v0.y); a2 += bf2f(v0.z); a3 += bf2f(v0.w);
    b0 += bf2f(v1.x); b1 += bf2f(v1.y); b2 += bf2f(v1.z); b3 += bf2f(v1.w);
    a0 += bf2f(v2.x); a1 += bf2f(v2.y); a2 += bf2f(v2.z); a3 += bf2f(v2.w);
    b0 += bf2f(v3.x); b1 += bf2f(v3.y); b2 += bf2f(v3.z); b3 += bf2f(v3.w);
    a0 += bf2f(v4.x); a1 += bf2f(v4.y); a2 += bf2f(v4.z); a3 += bf2f(v4.w);
    b0 += bf2f(v5.x); b1 += bf2f(v5.y); b2 += bf2f(v5.z); b3 += bf2f(v5.w);
    a0 += bf2f(v6.x); a1 += bf2f(v6.y); a2 += bf2f(v6.z); a3 += bf2f(v6.w);
    b0 += bf2f(v7.x); b1 += bf2f(v7.y); b2 += bf2f(v7.z); b3 += bf2f(v7.w);
  }
  a0 += b0; a1 += b1; a2 += b2; a3 += b3;
  a0 += __shfl_xor(a0, 32);
  a1 += __shfl_xor(a1, 32);
  a2 += __shfl_xor(a2, 32);
  a3 += __shfl_xor(a3, 32);

  if (l < 32) {
    float dv = dinv[n];
    ushort4 vs = *(const ushort4*)(h16 + ((size_t)n << 7) + dl);  // t[d]
    float4 bb = *(const float4*)(bias + dl);
    float o0 = fmaxf(fmaf(dv, a0 + bf2f(vs.x), bb.x), 0.f);
    float o1 = fmaxf(fmaf(dv, a1 + bf2f(vs.y), bb.y), 0.f);
    float o2 = fmaxf(fmaf(dv, a2 + bf2f(vs.z), bb.z), 0.f);
    float o3 = fmaxf(fmaf(dv, a3 + bf2f(vs.w), bb.w), 0.f);
    if (EMIT == 0) {
      ushort4 hi, lo;
      hi.x = f2bf(o0); lo.x = f2bf(o0 - bf2f(hi.x));
      hi.y = f2bf(o1); lo.y = f2bf(o1 - bf2f(hi.y));
      hi.z = f2bf(o2); lo.z = f2bf(o2 - bf2f(hi.z));
      hi.w = f2bf(o3); lo.w = f2bf(o3 - bf2f(hi.w));
      size_t base = (size_t)n * FD + dl;
      *(ushort4*)(yhi + base) = hi;
      *(ushort4*)(ylo + base) = lo;
    } else {
      // relu>=0: int-compare == float-compare for non-negative floats
      atomicMax(&pmax[dl + 0], __float_as_int(o0));
      atomicMax(&pmax[dl + 1], __float_as_int(o1));
      atomicMax(&pmax[dl + 2], __float_as_int(o2));
      atomicMax(&pmax[dl + 3], __float_as_int(o3));
    }
  }
  if (EMIT == 1) {
    __syncthreads();
    if (t < 128) {
      int gr = blockIdx.x >> 6;  // 64 blocks (256 nodes) per graph
      atomicMax((int*)pooled + gr * FD + t, pmax[t]);
    }
  }
}

// ---------------- MLP head ----------------

__global__ __launch_bounds__(128) void k_mlp(const float* __restrict__ pooled,
                                             const float* __restrict__ Wp1,
                                             const float* __restrict__ bp1,
                                             const float* __restrict__ Wp2,
                                             const float* __restrict__ bp2,
                                             float* __restrict__ out) {
  __shared__ float row[128];
  __shared__ float red[128];
  int g = blockIdx.x, t = threadIdx.x;
  row[t] = pooled[g * FD + t];
  __syncthreads();
  float acc = bp1[t];
#pragma unroll 8
  for (int k = 0; k < 128; k++) acc = fmaf(row[k], Wp1[k * FD + t], acc);
  acc = fmaxf(acc, 0.f);
  red[t] = acc * Wp2[t];
  __syncthreads();
  for (int st = 64; st > 0; st >>= 1) {
    if (t < st) red[t] += red[t + st];
    __syncthreads();
  }
  if (t == 0) out[g] = red[0] + bp2[0];
}

// ---------------- launch ----------------

extern "C" void kernel_launch(void* const* d_in, const int* in_sizes, int n_in,
                              void* d_out, int out_size, void* d_ws, size_t ws_size,
                              hipStream_t stream) {
  (void)in_sizes; (void)n_in; (void)out_size; (void)ws_size;

  const float* adj  = (const float*)d_in[0];
  const int*   edges= (const int*)d_in[1];
  const float* Wdec = (const float*)d_in[3];
  const float* bdec = (const float*)d_in[4];
  const float* Wc1  = (const float*)d_in[5];
  const float* bc1  = (const float*)d_in[6];
  const float* Wc2  = (const float*)d_in[7];
  const float* bc2  = (const float*)d_in[8];
  const float* Wp1  = (const float*)d_in[9];
  const float* bp1  = (const float*)d_in[10];
  const float* Wp2  = (const float*)d_in[11];
  const float* bp2  = (const float*)d_in[12];
  float* out = (float*)d_out;

  char* ws = (char*)d_ws;
  size_t off = 0;
  auto alloc = [&](size_t bytes) -> void* {
    void* p = ws + off;
    off += (bytes + 255) & ~(size_t)255;
    return p;
  };
  ushort* h16  = (ushort*)alloc((size_t)(NN + 1) * FD * 2);  // +1 zero row
  ushort* x1hi = (ushort*)alloc((size_t)NN * FD * 2);
  ushort* x1lo = (ushort*)alloc((size_t)NN * FD * 2);
  // hist | cnt | pooled contiguous -> single memset
  int*    hist = (int*)alloc((size_t)NN * 4);
  int*    cnt  = (int*)alloc((size_t)NN * 4);
  float*  pooled = (float*)alloc((size_t)NGRAPH * FD * 4);
  int*    offs = (int*)alloc((size_t)NN * 4);
  int*    bsum = (int*)alloc(256 * 4);
  uint*   ec   = (uint*)alloc((size_t)NEP_MAX * 4);    // 8.1 MB padded records
  float*  dinv = (float*)alloc((size_t)NN * 4);
  float*  wfused = (float*)alloc((size_t)KDEC * FD * 4);
  float*  bfused = (float*)alloc(FD * 4);
  ushort* wfh = (ushort*)alloc((size_t)KDEC * FD * 2);
  ushort* wfl = (ushort*)alloc((size_t)KDEC * FD * 2);
  ushort* w2h = (ushort*)alloc((size_t)FD * FD * 2);
  ushort* w2l = (ushort*)alloc((size_t)FD * FD * 2);

  hipMemsetAsync(hist, 0, (size_t)NN * 4 + (size_t)NN * 4 + (size_t)NGRAPH * FD * 4, stream);
  hipMemsetAsync(h16 + (size_t)NN * FD, 0, FD * 2, stream);  // zero row (dummy target)

  // histogram + ec dummy fill (fused)
  k_hist<<<NE / 256 + NEP_MAX / 1024, 256, 0, stream>>>(edges, hist, ec);
  // blocksum(padded) + Wfused=Wdec@Wc1 (+bfused) + prep(Wc2)
  k_misc1<<<448, 256, 0, stream>>>(hist, bsum, Wdec, Wc1, bdec, wfused, bfused,
                                   Wc2, w2h, w2l);
  // scanfinal(padded, scanb fused) + dinv(real) + prep(Wfused)
  k_misc2<<<384, 256, 0, stream>>>(hist, bsum, offs, dinv, wfused, wfh, wfl);
  k_scatter<<<NE / 256, 256, 0, stream>>>(edges, offs, cnt, ec);

  // t1 = dinv * (adj @ Wfused + bfused) -> bf16 table
  k_gemm<false><<<NN / 64, 256, 0, stream>>>(adj, nullptr, wfh, wfl, bfused, dinv, h16, KDEC);

  // x1 = relu(dinv*(sum t1 + t1_self) + bc1) -> hi/lo planes
  k_agg<0><<<NN / 4, 256, 0, stream>>>(h16, ec, offs, hist, dinv, bc1, x1hi, x1lo, nullptr);

  // t2 = dinv * (x1 @ Wc2) -> bf16 table
  k_gemm<true><<<NN / 64, 256, 0, stream>>>(x1hi, x1lo, w2h, w2l, nullptr, dinv, h16, FD);

  // pooled = segmax(relu(dinv*(sum t2 + t2_self) + bc2)) fused
  k_agg<1><<<NN / 4, 256, 0, stream>>>(h16, ec, offs, hist, dinv, bc2, nullptr, nullptr, pooled);

  // MLP head
  k_mlp<<<NGRAPH, 128, 0, stream>>>(pooled, Wp1, bp1, Wp2, bp2, out);
}

// Round 9
// 226.177 us; speedup vs baseline: 1.2224x; 1.2224x over previous
//
#include <hip/hip_runtime.h>
#include <hip/hip_fp16.h>
#include <cstdint>
#include <cstddef>

// Problem constants: B=256, C=1, NMAX=256 -> N=65536 nodes, E=N*16=1048576,
// EMB=HID=128, decode K = NMAX = 256.
#define NN   65536
#define NE   1048576
#define FD   128
#define KDEC 256
#define NGRAPH 256
// padded edge capacity: sum ceil(cnt/16)*16 <= NE + 15*NN
#define NEP_MAX (NE + 15 * NN)   // 2031616 records
#define DUMMY_SRC 65536u         // zero row index
#define EPB  4096                // edges per binning block
#define BCAP 4608                // per-bucket record capacity (mean 4096 + 8 sigma)

typedef __attribute__((ext_vector_type(8))) short s16x8;
typedef __attribute__((ext_vector_type(4))) float f32x4;

__device__ __forceinline__ ushort f2bf(float x) {
  uint u = __float_as_uint(x);
  uint r = (u + 0x7fffu + ((u >> 16) & 1u)) >> 16;  // RNE
  return (ushort)r;
}
__device__ __forceinline__ float bf2f(ushort h) {
  return __uint_as_float(((uint)h) << 16);
}

// ---------------- CSR build: hist + bucket-binning (fused) ----------------
// blocks 0..255: process 4096 edges each -> hist atomics + LDS-binned append
// into per-bucket (dst>>8) regions of binbuf (chunked, write-friendly).
// blocks 256..2239: fill ec with dummy records (padding slots).

__global__ __launch_bounds__(256) void k_histbin(const int* __restrict__ edges,
                                                 int* __restrict__ hist,
                                                 uint* __restrict__ ec,
                                                 uint* __restrict__ binbuf,
                                                 int* __restrict__ gbin) {
  int b = blockIdx.x, t = threadIdx.x;
  if (b >= 256) {
    int fi = (b - 256) * 1024 + t * 4;  // 1984 blocks * 1024 = NEP_MAX
    *(uint4*)(ec + fi) = make_uint4(DUMMY_SRC, DUMMY_SRC, DUMMY_SRC, DUMMY_SRC);
    return;
  }
  __shared__ int lcnt[256];
  __shared__ int gbase[256];
  lcnt[t] = 0;
  __syncthreads();
  uint rec[16], aux[16];
#pragma unroll
  for (int r = 0; r < 16; r++) {
    int i = b * EPB + r * 256 + t;
    int2 e = ((const int2*)edges)[i];
    atomicAdd(&hist[e.y], 1);
    int bucket = e.y >> 8;
    int lidx = atomicAdd(&lcnt[bucket], 1);
    rec[r] = ((uint)(e.y & 255) << 16) | (uint)e.x;
    aux[r] = ((uint)bucket << 16) | (uint)lidx;
  }
  __syncthreads();
  gbase[t] = atomicAdd(&gbin[t], lcnt[t]);
  __syncthreads();
#pragma unroll
  for (int r = 0; r < 16; r++) {
    int bucket = aux[r] >> 16;
    int lidx = aux[r] & 0xFFFF;
    binbuf[bucket * BCAP + gbase[bucket] + lidx] = rec[r];
  }
}

// phase 2: one block per bucket; sequential reads, writes confined to the
// bucket's contiguous ~27KB 64B-aligned CSR window (single writer, L2-local).
__global__ __launch_bounds__(256) void k_bscatter(const uint* __restrict__ binbuf,
                                                  const int* __restrict__ gbin,
                                                  const int* __restrict__ offs,
                                                  uint* __restrict__ ec) {
  __shared__ int cnt2[256];
  int b = blockIdx.x, t = threadIdx.x;
  cnt2[t] = 0;
  __syncthreads();
  int m = gbin[b];
  int nb = b << 8;
  for (int i = t; i < m; i += 256) {
    uint rec = binbuf[b * BCAP + i];
    int dlow = rec >> 16;
    int pos = offs[nb + dlow] + atomicAdd(&cnt2[dlow], 1);
    ec[pos] = rec & 0xFFFFu;
  }
}

// W pre-fragmentation helper (split bf16, fragment-major):
// dst(k,c) = ((k/32)*8 + c/16)*512 + ((c&15) + 16*((k&31)>>3))*8 + (k&7)
__device__ __forceinline__ void prep_one(const float* __restrict__ W,
                                         ushort* __restrict__ H,
                                         ushort* __restrict__ L, int i) {
  int k = i >> 7, c = i & 127;
  float w = W[i];
  ushort h = f2bf(w);
  ushort lo = f2bf(w - bf2f(h));
  size_t dst = ((size_t)((k >> 5) * 8 + (c >> 4)) * 64 +
                (size_t)((c & 15) + 16 * ((k & 31) >> 3))) * 8 + (k & 7);
  H[dst] = h;
  L[dst] = lo;
}

// misc1: blocks 0-255 blocksum over PADDED counts | 256-383 Wfused (+bfused) |
//        384-447 prep Wc2
__global__ __launch_bounds__(256) void k_misc1(const int* __restrict__ hist,
                                               int* __restrict__ bsum,
                                               const float* __restrict__ Wdec,
                                               const float* __restrict__ Wc1,
                                               const float* __restrict__ bdec,
                                               float* __restrict__ wfused,
                                               float* __restrict__ bfused,
                                               const float* __restrict__ Wc2,
                                               ushort* __restrict__ w2h,
                                               ushort* __restrict__ w2l) {
  int b = blockIdx.x, t = threadIdx.x;
  if (b < 256) {
    __shared__ int s[256];
    s[t] = (hist[b * 256 + t] + 15) & ~15;  // padded
    __syncthreads();
    for (int st = 128; st > 0; st >>= 1) {
      if (t < st) s[t] += s[t + st];
      __syncthreads();
    }
    if (t == 0) bsum[b] = s[0];
  } else if (b < 384) {
    int i = (b - 256) * 256 + t;  // 0..32767
    int k = i >> 7, c = i & 127;
    float acc = 0.f;
#pragma unroll 8
    for (int j = 0; j < 128; j++) acc = fmaf(Wdec[k * FD + j], Wc1[j * FD + c], acc);
    wfused[i] = acc;
    if (b == 256 && t < 128) {
      float ba = 0.f;
      for (int j = 0; j < 128; j++) ba = fmaf(bdec[j], Wc1[j * FD + t], ba);
      bfused[t] = ba;
    }
  } else {
    int i = (b - 384) * 256 + t;  // 0..16383
    prep_one(Wc2, w2h, w2l, i);
  }
}

// misc2: blocks 0-255 scanfinal over PADDED counts (scanb fused) + dinv(real) |
//        256-383 prep Wfused
__global__ __launch_bounds__(256) void k_misc2(const int* __restrict__ hist,
                                               const int* __restrict__ bsum,
                                               int* __restrict__ offs,
                                               float* __restrict__ dinv,
                                               const float* __restrict__ wfused,
                                               ushort* __restrict__ wfh,
                                               ushort* __restrict__ wfl) {
  int b = blockIdx.x, t = threadIdx.x;
  if (b < 256) {
    __shared__ int sb[256];
    __shared__ int s[256];
    sb[t] = bsum[t];
    int v = hist[b * 256 + t];
    int vp = (v + 15) & ~15;
    s[t] = vp;
    __syncthreads();
    for (int off = 1; off < 256; off <<= 1) {
      int addb = (t >= off) ? sb[t - off] : 0;
      int add = (t >= off) ? s[t - off] : 0;
      __syncthreads();
      sb[t] += addb;
      s[t] += add;
      __syncthreads();
    }
    int pb = (b > 0) ? sb[b - 1] : 0;
    offs[b * 256 + t] = pb + s[t] - vp;  // padded exclusive offsets
    dinv[b * 256 + t] = rsqrtf((float)(v + 1));
  } else {
    int i = (b - 256) * 256 + t;  // 0..32767
    prep_one(wfused, wfh, wfl, i);
  }
}

// ---------------- split-bf16 MFMA GEMM: Y[M,128] = X[M,K] @ W[K,128] (+bias) ----
// BM=64: 256 threads = 4 waves, wave = one 16-row m-frag. ASPLIT: A pre-split
// bf16 planes; else fp32 A. Output row-major bf16, row-scaled by scale[] if set
// (pre-scaled gather table t = dinv*h).

template <bool ASPLIT>
__global__ __launch_bounds__(256) void k_gemm(const void* __restrict__ A0,
                                              const void* __restrict__ A1,
                                              const ushort* __restrict__ Whi,
                                              const ushort* __restrict__ Wlo,
                                              const float* __restrict__ bias,
                                              const float* __restrict__ scale,
                                              ushort* __restrict__ Y, int K) {
  const int t = threadIdx.x;
  const int w = t >> 6;
  const int l = t & 63;
  const int lr = l & 15;   // row-in-frag (A) / col-in-frag (B,C)
  const int kg = l >> 4;   // k-group 0..3
  const int r0 = blockIdx.x * 64 + w * 16;

  f32x4 acc[8];
#pragma unroll
  for (int nb = 0; nb < 8; nb++) acc[nb] = (f32x4)0.f;

  for (int ks = 0; ks < K; ks += 32) {
    s16x8 ah, al;
    if (ASPLIT) {
      size_t base = (size_t)(r0 + lr) * K + ks + kg * 8;
      ah = *(const s16x8*)((const ushort*)A0 + base);
      al = *(const s16x8*)((const ushort*)A1 + base);
    } else {
      const float* xp = (const float*)A0 + (size_t)(r0 + lr) * K + ks + kg * 8;
      f32x4 x0 = *(const f32x4*)xp;
      f32x4 x1 = *(const f32x4*)(xp + 4);
      float xv[8] = {x0.x, x0.y, x0.z, x0.w, x1.x, x1.y, x1.z, x1.w};
      union { ushort u[8]; s16x8 v; } H, L;
#pragma unroll
      for (int e = 0; e < 8; e++) {
        ushort h = f2bf(xv[e]);
        H.u[e] = h;
        L.u[e] = f2bf(xv[e] - bf2f(h));
      }
      ah = H.v;
      al = L.v;
    }
    const size_t bbase = (size_t)(ks >> 5) * 4096 + (size_t)l * 8;
#pragma unroll
    for (int nb = 0; nb < 8; nb++) {
      s16x8 bh = *(const s16x8*)(Whi + bbase + nb * 512);
      s16x8 bl = *(const s16x8*)(Wlo + bbase + nb * 512);
      acc[nb] = __builtin_amdgcn_mfma_f32_16x16x32_bf16(ah, bh, acc[nb], 0, 0, 0);
      acc[nb] = __builtin_amdgcn_mfma_f32_16x16x32_bf16(ah, bl, acc[nb], 0, 0, 0);
      acc[nb] = __builtin_amdgcn_mfma_f32_16x16x32_bf16(al, bh, acc[nb], 0, 0, 0);
    }
  }

  // epilogue: C/D col = lr (within frag), row = kg*4 + reg
  float dvr[4];
#pragma unroll
  for (int r = 0; r < 4; r++)
    dvr[r] = scale ? scale[r0 + kg * 4 + r] : 1.f;

#pragma unroll
  for (int nb = 0; nb < 8; nb++) {
    int col = nb * 16 + lr;
    float bv = bias ? bias[col] : 0.f;
#pragma unroll
    for (int r = 0; r < 4; r++) {
      size_t row = (size_t)(r0 + kg * 4 + r);
      Y[row * FD + col] = f2bf((acc[nb][r] + bv) * dvr[r]);
    }
  }
}

// ---------------- GCN aggregation: wave-per-node, UNIFORM 8-deep pipeline ------
// Table t = dinv*h, bf16 [NN+1][128] (row NN = zeros, dummy-pad target).
// Wave = 1 node; lane l: edge parity half=l>>5, dims dl=(l&31)*4 (ushort4).
// Segments padded to multiples of 16 -> single uniform loop, 8 gathers in
// flight per lane-half for EVERY node, zero remainder/divergence.
// out[d] = relu( dinv[d]*(sum_e t[src_e] + t[d]) + b )
// EMIT=0: write hi/lo bf16 planes. EMIT=1: fused segment-max pooling.

template <int EMIT>
__global__ __launch_bounds__(256) void k_agg(const ushort* __restrict__ h16,
                                             const uint* __restrict__ ec,
                                             const int* __restrict__ offs,
                                             const int* __restrict__ hist,
                                             const float* __restrict__ dinv,
                                             const float* __restrict__ bias,
                                             ushort* __restrict__ yhi,
                                             ushort* __restrict__ ylo,
                                             float* __restrict__ pooled) {
  __shared__ int pmax[128];
  const int t = threadIdx.x;
  if (EMIT == 1) {
    if (t < 128) pmax[t] = 0;
    __syncthreads();
  }
  const int n = blockIdx.x * 4 + (t >> 6);
  const int l = t & 63;
  const int half = l >> 5;
  const int dl = (l & 31) * 4;

  const int cnt_p = (hist[n] + 15) & ~15;  // padded count
  const uint* ep = ec + offs[n];

  float a0 = 0.f, a1 = 0.f, a2 = 0.f, a3 = 0.f;
  float b0 = 0.f, b1 = 0.f, b2 = 0.f, b3 = 0.f;
  for (int i = half; i < cnt_p; i += 16) {
    uint s0 = ep[i];
    uint s1 = ep[i + 2];
    uint s2 = ep[i + 4];
    uint s3 = ep[i + 6];
    uint s4 = ep[i + 8];
    uint s5 = ep[i + 10];
    uint s6 = ep[i + 12];
    uint s7 = ep[i + 14];
    ushort4 v0 = *(const ushort4*)(h16 + ((size_t)s0 << 7) + dl);
    ushort4 v1 = *(const ushort4*)(h16 + ((size_t)s1 << 7) + dl);
    ushort4 v2 = *(const ushort4*)(h16 + ((size_t)s2 << 7) + dl);
    ushort4 v3 = *(const ushort4*)(h16 + ((size_t)s3 << 7) + dl);
    ushort4 v4 = *(const ushort4*)(h16 + ((size_t)s4 << 7) + dl);
    ushort4 v5 = *(const ushort4*)(h16 + ((size_t)s5 << 7) + dl);
    ushort4 v6 = *(const ushort4*)(h16 + ((size_t)s6 << 7) + dl);
    ushort4 v7 = *(const ushort4*)(h16 + ((size_t)s7 << 7) + dl);
    a0 += bf2f(v0.x); a1 += bf2f(v0.y); a2 += bf2f(v0.z); a3 += bf2f(v0.w);
    b0 += bf2f(v1.x); b1 += bf2f(v1.y); b2 += bf2f(v1.z); b3 += bf2f(v1.w);
    a0 += bf2f(v2.x); a1 += bf2f(v2.y); a2 += bf2f(v2.z); a3 += bf2f(v2.w);
    b0 += bf2f(v3.x); b1 += bf2f(v3.y); b2 += bf2f(v3.z); b3 += bf2f(v3.w);
    a0 += bf2f(v4.x); a1 += bf2f(v4.y); a2 += bf2f(v4.z); a3 += bf2f(v4.w);
    b0 += bf2f(v5.x); b1 += bf2f(v5.y); b2 += bf2f(v5.z); b3 += bf2f(v5.w);
    a0 += bf2f(v6.x); a1 += bf2f(v6.y); a2 += bf2f(v6.z); a3 += bf2f(v6.w);
    b0 += bf2f(v7.x); b1 += bf2f(v7.y); b2 += bf2f(v7.z); b3 += bf2f(v7.w);
  }
  a0 += b0; a1 += b1; a2 += b2; a3 += b3;
  a0 += __shfl_xor(a0, 32);
  a1 += __shfl_xor(a1, 32);
  a2 += __shfl_xor(a2, 32);
  a3 += __shfl_xor(a3, 32);

  if (l < 32) {
    float dv = dinv[n];
    ushort4 vs = *(const ushort4*)(h16 + ((size_t)n << 7) + dl);  // t[d]
    float4 bb = *(const float4*)(bias + dl);
    float o0 = fmaxf(fmaf(dv, a0 + bf2f(vs.x), bb.x), 0.f);
    float o1 = fmaxf(fmaf(dv, a1 + bf2f(vs.y), bb.y), 0.f);
    float o2 = fmaxf(fmaf(dv, a2 + bf2f(vs.z), bb.z), 0.f);
    float o3 = fmaxf(fmaf(dv, a3 + bf2f(vs.w), bb.w), 0.f);
    if (EMIT == 0) {
      ushort4 hi, lo;
      hi.x = f2bf(o0); lo.x = f2bf(o0 - bf2f(hi.x));
      hi.y = f2bf(o1); lo.y = f2bf(o1 - bf2f(hi.y));
      hi.z = f2bf(o2); lo.z = f2bf(o2 - bf2f(hi.z));
      hi.w = f2bf(o3); lo.w = f2bf(o3 - bf2f(hi.w));
      size_t base = (size_t)n * FD + dl;
      *(ushort4*)(yhi + base) = hi;
      *(ushort4*)(ylo + base) = lo;
    } else {
      // relu>=0: int-compare == float-compare for non-negative floats
      atomicMax(&pmax[dl + 0], __float_as_int(o0));
      atomicMax(&pmax[dl + 1], __float_as_int(o1));
      atomicMax(&pmax[dl + 2], __float_as_int(o2));
      atomicMax(&pmax[dl + 3], __float_as_int(o3));
    }
  }
  if (EMIT == 1) {
    __syncthreads();
    if (t < 128) {
      int gr = blockIdx.x >> 6;  // 64 blocks (256 nodes) per graph
      atomicMax((int*)pooled + gr * FD + t, pmax[t]);
    }
  }
}

// ---------------- MLP head ----------------

__global__ __launch_bounds__(128) void k_mlp(const float* __restrict__ pooled,
                                             const float* __restrict__ Wp1,
                                             const float* __restrict__ bp1,
                                             const float* __restrict__ Wp2,
                                             const float* __restrict__ bp2,
                                             float* __restrict__ out) {
  __shared__ float row[128];
  __shared__ float red[128];
  int g = blockIdx.x, t = threadIdx.x;
  row[t] = pooled[g * FD + t];
  __syncthreads();
  float acc = bp1[t];
#pragma unroll 8
  for (int k = 0; k < 128; k++) acc = fmaf(row[k], Wp1[k * FD + t], acc);
  acc = fmaxf(acc, 0.f);
  red[t] = acc * Wp2[t];
  __syncthreads();
  for (int st = 64; st > 0; st >>= 1) {
    if (t < st) red[t] += red[t + st];
    __syncthreads();
  }
  if (t == 0) out[g] = red[0] + bp2[0];
}

// ---------------- launch ----------------

extern "C" void kernel_launch(void* const* d_in, const int* in_sizes, int n_in,
                              void* d_out, int out_size, void* d_ws, size_t ws_size,
                              hipStream_t stream) {
  (void)in_sizes; (void)n_in; (void)out_size; (void)ws_size;

  const float* adj  = (const float*)d_in[0];
  const int*   edges= (const int*)d_in[1];
  const float* Wdec = (const float*)d_in[3];
  const float* bdec = (const float*)d_in[4];
  const float* Wc1  = (const float*)d_in[5];
  const float* bc1  = (const float*)d_in[6];
  const float* Wc2  = (const float*)d_in[7];
  const float* bc2  = (const float*)d_in[8];
  const float* Wp1  = (const float*)d_in[9];
  const float* bp1  = (const float*)d_in[10];
  const float* Wp2  = (const float*)d_in[11];
  const float* bp2  = (const float*)d_in[12];
  float* out = (float*)d_out;

  char* ws = (char*)d_ws;
  size_t off = 0;
  auto alloc = [&](size_t bytes) -> void* {
    void* p = ws + off;
    off += (bytes + 255) & ~(size_t)255;
    return p;
  };
  ushort* h16  = (ushort*)alloc((size_t)(NN + 1) * FD * 2);  // +1 zero row
  ushort* x1hi = (ushort*)alloc((size_t)NN * FD * 2);
  ushort* x1lo = (ushort*)alloc((size_t)NN * FD * 2);
  // hist | pooled | gbin contiguous -> single memset
  int*    hist = (int*)alloc((size_t)NN * 4);
  float*  pooled = (float*)alloc((size_t)NGRAPH * FD * 4);
  int*    gbin = (int*)alloc(256 * 4);
  int*    offs = (int*)alloc((size_t)NN * 4);
  int*    bsum = (int*)alloc(256 * 4);
  uint*   ec   = (uint*)alloc((size_t)NEP_MAX * 4);    // 8.1 MB padded records
  uint*   binbuf = (uint*)alloc((size_t)256 * BCAP * 4);  // 4.7 MB bucket bins
  float*  dinv = (float*)alloc((size_t)NN * 4);
  float*  wfused = (float*)alloc((size_t)KDEC * FD * 4);
  float*  bfused = (float*)alloc(FD * 4);
  ushort* wfh = (ushort*)alloc((size_t)KDEC * FD * 2);
  ushort* wfl = (ushort*)alloc((size_t)KDEC * FD * 2);
  ushort* w2h = (ushort*)alloc((size_t)FD * FD * 2);
  ushort* w2l = (ushort*)alloc((size_t)FD * FD * 2);

  hipMemsetAsync(hist, 0, (size_t)NN * 4 + (size_t)NGRAPH * FD * 4 + 256 * 4, stream);
  hipMemsetAsync(h16 + (size_t)NN * FD, 0, FD * 2, stream);  // zero row (dummy target)

  // histogram + LDS-binned bucket append + ec dummy fill (one kernel)
  k_histbin<<<256 + NEP_MAX / 1024, 256, 0, stream>>>(edges, hist, ec, binbuf, gbin);
  // blocksum(padded) + Wfused=Wdec@Wc1 (+bfused) + prep(Wc2)
  k_misc1<<<448, 256, 0, stream>>>(hist, bsum, Wdec, Wc1, bdec, wfused, bfused,
                                   Wc2, w2h, w2l);
  // scanfinal(padded, scanb fused) + dinv(real) + prep(Wfused)
  k_misc2<<<384, 256, 0, stream>>>(hist, bsum, offs, dinv, wfused, wfh, wfl);
  // bucket -> exact CSR position (L2-local windows, no cross-XCD sharing)
  k_bscatter<<<256, 256, 0, stream>>>(binbuf, gbin, offs, ec);

  // t1 = dinv * (adj @ Wfused + bfused) -> bf16 table
  k_gemm<false><<<NN / 64, 256, 0, stream>>>(adj, nullptr, wfh, wfl, bfused, dinv, h16, KDEC);

  // x1 = relu(dinv*(sum t1 + t1_self) + bc1) -> hi/lo planes
  k_agg<0><<<NN / 4, 256, 0, stream>>>(h16, ec, offs, hist, dinv, bc1, x1hi, x1lo, nullptr);

  // t2 = dinv * (x1 @ Wc2) -> bf16 table
  k_gemm<true><<<NN / 64, 256, 0, stream>>>(x1hi, x1lo, w2h, w2l, nullptr, dinv, h16, FD);

  // pooled = segmax(relu(dinv*(sum t2 + t2_self) + bc2)) fused
  k_agg<1><<<NN / 4, 256, 0, stream>>>(h16, ec, offs, hist, dinv, bc2, nullptr, nullptr, pooled);

  // MLP head
  k_mlp<<<NGRAPH, 128, 0, stream>>>(pooled, Wp1, bp1, Wp2, bp2, out);
}

// Round 10
// 224.135 us; speedup vs baseline: 1.2335x; 1.0091x over previous
//
#include <hip/hip_runtime.h>
#include <hip/hip_fp16.h>
#include <cstdint>
#include <cstddef>

// Problem constants: B=256, C=1, NMAX=256 -> N=65536 nodes, E=N*16=1048576,
// EMB=HID=128, decode K = NMAX = 256.
#define NN   65536
#define NE   1048576
#define FD   128
#define KDEC 256
#define NGRAPH 256
// padded edge capacity: sum ceil(cnt/16)*16 <= NE + 15*NN
#define NEP_MAX (NE + 15 * NN)   // 2031616 records (= 4096 * 496)
#define DUMMY_SRC 65536u         // zero row index
#define EPB  4096                // edges per binning block
#define BCAP 4608                // per-bucket record capacity (mean 4096 + 8 sigma)

typedef __attribute__((ext_vector_type(8))) short s16x8;
typedef __attribute__((ext_vector_type(4))) float f32x4;

__device__ __forceinline__ ushort f2bf(float x) {
  uint u = __float_as_uint(x);
  uint r = (u + 0x7fffu + ((u >> 16) & 1u)) >> 16;  // RNE
  return (ushort)r;
}
__device__ __forceinline__ float bf2f(ushort h) {
  return __uint_as_float(((uint)h) << 16);
}

// ---------------- CSR build: hist + radix-partition binning (fused) ----------
// blocks 0..255 (1024 thr): 4096 edges each. Pass 1: global hist atomics +
// LDS bucket count (lidx captured). Scan. Pass 2: place records into LDS
// sorted[] in bucket order (random 4B writes go to LDS, not global). Pass 3:
// stream sorted[] out in slot order -> consecutive slots = consecutive global
// dests = coalesced full-line stores into each bucket's binbuf chunk.
// blocks 256..751: fill ec with dummy records (padding slots).

__global__ __launch_bounds__(1024) void k_histbin(const int* __restrict__ edges,
                                                  int* __restrict__ hist,
                                                  uint* __restrict__ ec,
                                                  uint* __restrict__ binbuf,
                                                  int* __restrict__ gbin) {
  const int b = blockIdx.x, t = threadIdx.x;
  if (b >= 256) {
    int fi = (b - 256) * 4096 + t * 4;  // 496 blocks * 4096 = NEP_MAX
    *(uint4*)(ec + fi) = make_uint4(DUMMY_SRC, DUMMY_SRC, DUMMY_SRC, DUMMY_SRC);
    return;
  }
  __shared__ int lcnt[256];
  __shared__ int lsum[256];   // inclusive prefix of lcnt
  __shared__ int gbase[256];
  __shared__ uint sorted[EPB];

  if (t < 256) lcnt[t] = 0;
  __syncthreads();

  uint rec[4];
  ushort bkt[4], lidx[4];
#pragma unroll
  for (int r = 0; r < 4; r++) {
    int i = b * EPB + r * 1024 + t;
    int2 e = ((const int2*)edges)[i];
    atomicAdd(&hist[e.y], 1);
    int bucket = e.y >> 8;
    int li = atomicAdd(&lcnt[bucket], 1);
    rec[r] = ((uint)bucket << 24) | ((uint)(e.y & 255) << 16) | (uint)e.x;
    bkt[r] = (ushort)bucket;
    lidx[r] = (ushort)li;
  }
  __syncthreads();

  // inclusive scan of lcnt -> lsum (first 256 threads; full-block barriers)
  if (t < 256) lsum[t] = lcnt[t];
  __syncthreads();
  for (int off = 1; off < 256; off <<= 1) {
    int v = 0;
    if (t < 256 && t >= off) v = lsum[t - off];
    __syncthreads();
    if (t < 256) lsum[t] += v;
    __syncthreads();
  }
  // reserve global bucket space (one atomic per bucket per block)
  if (t < 256) gbase[t] = atomicAdd(&gbin[t], lcnt[t]);
  __syncthreads();

  // pass 2: place into LDS sorted buffer (exclusive base = lsum - lcnt)
#pragma unroll
  for (int r = 0; r < 4; r++) {
    int B = bkt[r];
    sorted[lsum[B] - lcnt[B] + lidx[r]] = rec[r];
  }
  __syncthreads();

  // pass 3: stream out in slot order -> coalesced chunked stores
  for (int s = t; s < EPB; s += 1024) {
    uint v = sorted[s];
    int B = v >> 24;
    int ex = lsum[B] - lcnt[B];
    binbuf[B * BCAP + gbase[B] + (s - ex)] = v & 0xFFFFFFu;
  }
}

// phase 2: one block per bucket; sequential reads, writes confined to the
// bucket's contiguous ~27KB 64B-aligned CSR window (single writer, L2-local).
__global__ __launch_bounds__(256) void k_bscatter(const uint* __restrict__ binbuf,
                                                  const int* __restrict__ gbin,
                                                  const int* __restrict__ offs,
                                                  uint* __restrict__ ec) {
  __shared__ int cnt2[256];
  int b = blockIdx.x, t = threadIdx.x;
  cnt2[t] = 0;
  __syncthreads();
  int m = gbin[b];
  int nb = b << 8;
  for (int i = t; i < m; i += 256) {
    uint rec = binbuf[b * BCAP + i];
    int dlow = rec >> 16;
    int pos = offs[nb + dlow] + atomicAdd(&cnt2[dlow], 1);
    ec[pos] = rec & 0xFFFFu;
  }
}

// W pre-fragmentation helper (split bf16, fragment-major):
// dst(k,c) = ((k/32)*8 + c/16)*512 + ((c&15) + 16*((k&31)>>3))*8 + (k&7)
__device__ __forceinline__ void prep_one(const float* __restrict__ W,
                                         ushort* __restrict__ H,
                                         ushort* __restrict__ L, int i) {
  int k = i >> 7, c = i & 127;
  float w = W[i];
  ushort h = f2bf(w);
  ushort lo = f2bf(w - bf2f(h));
  size_t dst = ((size_t)((k >> 5) * 8 + (c >> 4)) * 64 +
                (size_t)((c & 15) + 16 * ((k & 31) >> 3))) * 8 + (k & 7);
  H[dst] = h;
  L[dst] = lo;
}

// misc1: blocks 0-255 blocksum over PADDED counts | 256-383 Wfused (+bfused) |
//        384-447 prep Wc2
__global__ __launch_bounds__(256) void k_misc1(const int* __restrict__ hist,
                                               int* __restrict__ bsum,
                                               const float* __restrict__ Wdec,
                                               const float* __restrict__ Wc1,
                                               const float* __restrict__ bdec,
                                               float* __restrict__ wfused,
                                               float* __restrict__ bfused,
                                               const float* __restrict__ Wc2,
                                               ushort* __restrict__ w2h,
                                               ushort* __restrict__ w2l) {
  int b = blockIdx.x, t = threadIdx.x;
  if (b < 256) {
    __shared__ int s[256];
    s[t] = (hist[b * 256 + t] + 15) & ~15;  // padded
    __syncthreads();
    for (int st = 128; st > 0; st >>= 1) {
      if (t < st) s[t] += s[t + st];
      __syncthreads();
    }
    if (t == 0) bsum[b] = s[0];
  } else if (b < 384) {
    int i = (b - 256) * 256 + t;  // 0..32767
    int k = i >> 7, c = i & 127;
    float acc = 0.f;
#pragma unroll 8
    for (int j = 0; j < 128; j++) acc = fmaf(Wdec[k * FD + j], Wc1[j * FD + c], acc);
    wfused[i] = acc;
    if (b == 256 && t < 128) {
      float ba = 0.f;
      for (int j = 0; j < 128; j++) ba = fmaf(bdec[j], Wc1[j * FD + t], ba);
      bfused[t] = ba;
    }
  } else {
    int i = (b - 384) * 256 + t;  // 0..16383
    prep_one(Wc2, w2h, w2l, i);
  }
}

// misc2: blocks 0-255 scanfinal over PADDED counts (scanb fused) + dinv(real) |
//        256-383 prep Wfused
__global__ __launch_bounds__(256) void k_misc2(const int* __restrict__ hist,
                                               const int* __restrict__ bsum,
                                               int* __restrict__ offs,
                                               float* __restrict__ dinv,
                                               const float* __restrict__ wfused,
                                               ushort* __restrict__ wfh,
                                               ushort* __restrict__ wfl) {
  int b = blockIdx.x, t = threadIdx.x;
  if (b < 256) {
    __shared__ int sb[256];
    __shared__ int s[256];
    sb[t] = bsum[t];
    int v = hist[b * 256 + t];
    int vp = (v + 15) & ~15;
    s[t] = vp;
    __syncthreads();
    for (int off = 1; off < 256; off <<= 1) {
      int addb = (t >= off) ? sb[t - off] : 0;
      int add = (t >= off) ? s[t - off] : 0;
      __syncthreads();
      sb[t] += addb;
      s[t] += add;
      __syncthreads();
    }
    int pb = (b > 0) ? sb[b - 1] : 0;
    offs[b * 256 + t] = pb + s[t] - vp;  // padded exclusive offsets
    dinv[b * 256 + t] = rsqrtf((float)(v + 1));
  } else {
    int i = (b - 256) * 256 + t;  // 0..32767
    prep_one(wfused, wfh, wfl, i);
  }
}

// ---------------- split-bf16 MFMA GEMM: Y[M,128] = X[M,K] @ W[K,128] (+bias) ----
// BM=64: 256 threads = 4 waves, wave = one 16-row m-frag. ASPLIT: A pre-split
// bf16 planes; else fp32 A. Output row-major bf16, row-scaled by scale[] if set
// (pre-scaled gather table t = dinv*h).

template <bool ASPLIT>
__global__ __launch_bounds__(256) void k_gemm(const void* __restrict__ A0,
                                              const void* __restrict__ A1,
                                              const ushort* __restrict__ Whi,
                                              const ushort* __restrict__ Wlo,
                                              const float* __restrict__ bias,
                                              const float* __restrict__ scale,
                                              ushort* __restrict__ Y, int K) {
  const int t = threadIdx.x;
  const int w = t >> 6;
  const int l = t & 63;
  const int lr = l & 15;   // row-in-frag (A) / col-in-frag (B,C)
  const int kg = l >> 4;   // k-group 0..3
  const int r0 = blockIdx.x * 64 + w * 16;

  f32x4 acc[8];
#pragma unroll
  for (int nb = 0; nb < 8; nb++) acc[nb] = (f32x4)0.f;

  for (int ks = 0; ks < K; ks += 32) {
    s16x8 ah, al;
    if (ASPLIT) {
      size_t base = (size_t)(r0 + lr) * K + ks + kg * 8;
      ah = *(const s16x8*)((const ushort*)A0 + base);
      al = *(const s16x8*)((const ushort*)A1 + base);
    } else {
      const float* xp = (const float*)A0 + (size_t)(r0 + lr) * K + ks + kg * 8;
      f32x4 x0 = *(const f32x4*)xp;
      f32x4 x1 = *(const f32x4*)(xp + 4);
      float xv[8] = {x0.x, x0.y, x0.z, x0.w, x1.x, x1.y, x1.z, x1.w};
      union { ushort u[8]; s16x8 v; } H, L;
#pragma unroll
      for (int e = 0; e < 8; e++) {
        ushort h = f2bf(xv[e]);
        H.u[e] = h;
        L.u[e] = f2bf(xv[e] - bf2f(h));
      }
      ah = H.v;
      al = L.v;
    }
    const size_t bbase = (size_t)(ks >> 5) * 4096 + (size_t)l * 8;
#pragma unroll
    for (int nb = 0; nb < 8; nb++) {
      s16x8 bh = *(const s16x8*)(Whi + bbase + nb * 512);
      s16x8 bl = *(const s16x8*)(Wlo + bbase + nb * 512);
      acc[nb] = __builtin_amdgcn_mfma_f32_16x16x32_bf16(ah, bh, acc[nb], 0, 0, 0);
      acc[nb] = __builtin_amdgcn_mfma_f32_16x16x32_bf16(ah, bl, acc[nb], 0, 0, 0);
      acc[nb] = __builtin_amdgcn_mfma_f32_16x16x32_bf16(al, bh, acc[nb], 0, 0, 0);
    }
  }

  // epilogue: C/D col = lr (within frag), row = kg*4 + reg
  float dvr[4];
#pragma unroll
  for (int r = 0; r < 4; r++)
    dvr[r] = scale ? scale[r0 + kg * 4 + r] : 1.f;

#pragma unroll
  for (int nb = 0; nb < 8; nb++) {
    int col = nb * 16 + lr;
    float bv = bias ? bias[col] : 0.f;
#pragma unroll
    for (int r = 0; r < 4; r++) {
      size_t row = (size_t)(r0 + kg * 4 + r);
      Y[row * FD + col] = f2bf((acc[nb][r] + bv) * dvr[r]);
    }
  }
}

// ---------------- GCN aggregation: wave-per-node, UNIFORM 8-deep pipeline ------
// Table t = dinv*h, bf16 [NN+1][128] (row NN = zeros, dummy-pad target).
// Wave = 1 node; lane l: edge parity half=l>>5, dims dl=(l&31)*4 (ushort4).
// Segments padded to multiples of 16 -> single uniform loop, 8 gathers in
// flight per lane-half for EVERY node, zero remainder/divergence.
// out[d] = relu( dinv[d]*(sum_e t[src_e] + t[d]) + b )
// EMIT=0: write hi/lo bf16 planes. EMIT=1: fused segment-max pooling.

template <int EMIT>
__global__ __launch_bounds__(256) void k_agg(const ushort* __restrict__ h16,
                                             const uint* __restrict__ ec,
                                             const int* __restrict__ offs,
                                             const int* __restrict__ hist,
                                             const float* __restrict__ dinv,
                                             const float* __restrict__ bias,
                                             ushort* __restrict__ yhi,
                                             ushort* __restrict__ ylo,
                                             float* __restrict__ pooled) {
  __shared__ int pmax[128];
  const int t = threadIdx.x;
  if (EMIT == 1) {
    if (t < 128) pmax[t] = 0;
    __syncthreads();
  }
  const int n = blockIdx.x * 4 + (t >> 6);
  const int l = t & 63;
  const int half = l >> 5;
  const int dl = (l & 31) * 4;

  const int cnt_p = (hist[n] + 15) & ~15;  // padded count
  const uint* ep = ec + offs[n];

  float a0 = 0.f, a1 = 0.f, a2 = 0.f, a3 = 0.f;
  float b0 = 0.f, b1 = 0.f, b2 = 0.f, b3 = 0.f;
  for (int i = half; i < cnt_p; i += 16) {
    uint s0 = ep[i];
    uint s1 = ep[i + 2];
    uint s2 = ep[i + 4];
    uint s3 = ep[i + 6];
    uint s4 = ep[i + 8];
    uint s5 = ep[i + 10];
    uint s6 = ep[i + 12];
    uint s7 = ep[i + 14];
    ushort4 v0 = *(const ushort4*)(h16 + ((size_t)s0 << 7) + dl);
    ushort4 v1 = *(const ushort4*)(h16 + ((size_t)s1 << 7) + dl);
    ushort4 v2 = *(const ushort4*)(h16 + ((size_t)s2 << 7) + dl);
    ushort4 v3 = *(const ushort4*)(h16 + ((size_t)s3 << 7) + dl);
    ushort4 v4 = *(const ushort4*)(h16 + ((size_t)s4 << 7) + dl);
    ushort4 v5 = *(const ushort4*)(h16 + ((size_t)s5 << 7) + dl);
    ushort4 v6 = *(const ushort4*)(h16 + ((size_t)s6 << 7) + dl);
    ushort4 v7 = *(const ushort4*)(h16 + ((size_t)s7 << 7) + dl);
    a0 += bf2f(v0.x); a1 += bf2f(v0.y); a2 += bf2f(v0.z); a3 += bf2f(v0.w);
    b0 += bf2f(v1.x); b1 += bf2f(v1.y); b2 += bf2f(v1.z); b3 += bf2f(v1.w);
    a0 += bf2f(v2.x); a1 += bf2f(v2.y); a2 += bf2f(v2.z); a3 += bf2f(v2.w);
    b0 += bf2f(v3.x); b1 += bf2f(v3.y); b2 += bf2f(v3.z); b3 += bf2f(v3.w);
    a0 += bf2f(v4.x); a1 += bf2f(v4.y); a2 += bf2f(v4.z); a3 += bf2f(v4.w);
    b0 += bf2f(v5.x); b1 += bf2f(v5.y); b2 += bf2f(v5.z); b3 += bf2f(v5.w);
    a0 += bf2f(v6.x); a1 += bf2f(v6.y); a2 += bf2f(v6.z); a3 += bf2f(v6.w);
    b0 += bf2f(v7.x); b1 += bf2f(v7.y); b2 += bf2f(v7.z); b3 += bf2f(v7.w);
  }
  a0 += b0; a1 += b1; a2 += b2; a3 += b3;
  a0 += __shfl_xor(a0, 32);
  a1 += __shfl_xor(a1, 32);
  a2 += __shfl_xor(a2, 32);
  a3 += __shfl_xor(a3, 32);

  if (l < 32) {
    float dv = dinv[n];
    ushort4 vs = *(const ushort4*)(h16 + ((size_t)n << 7) + dl);  // t[d]
    float4 bb = *(const float4*)(bias + dl);
    float o0 = fmaxf(fmaf(dv, a0 + bf2f(vs.x), bb.x), 0.f);
    float o1 = fmaxf(fmaf(dv, a1 + bf2f(vs.y), bb.y), 0.f);
    float o2 = fmaxf(fmaf(dv, a2 + bf2f(vs.z), bb.z), 0.f);
    float o3 = fmaxf(fmaf(dv, a3 + bf2f(vs.w), bb.w), 0.f);
    if (EMIT == 0) {
      ushort4 hi, lo;
      hi.x = f2bf(o0); lo.x = f2bf(o0 - bf2f(hi.x));
      hi.y = f2bf(o1); lo.y = f2bf(o1 - bf2f(hi.y));
      hi.z = f2bf(o2); lo.z = f2bf(o2 - bf2f(hi.z));
      hi.w = f2bf(o3); lo.w = f2bf(o3 - bf2f(hi.w));
      size_t base = (size_t)n * FD + dl;
      *(ushort4*)(yhi + base) = hi;
      *(ushort4*)(ylo + base) = lo;
    } else {
      // relu>=0: int-compare == float-compare for non-negative floats
      atomicMax(&pmax[dl + 0], __float_as_int(o0));
      atomicMax(&pmax[dl + 1], __float_as_int(o1));
      atomicMax(&pmax[dl + 2], __float_as_int(o2));
      atomicMax(&pmax[dl + 3], __float_as_int(o3));
    }
  }
  if (EMIT == 1) {
    __syncthreads();
    if (t < 128) {
      int gr = blockIdx.x >> 6;  // 64 blocks (256 nodes) per graph
      atomicMax((int*)pooled + gr * FD + t, pmax[t]);
    }
  }
}

// ---------------- MLP head ----------------

__global__ __launch_bounds__(128) void k_mlp(const float* __restrict__ pooled,
                                             const float* __restrict__ Wp1,
                                             const float* __restrict__ bp1,
                                             const float* __restrict__ Wp2,
                                             const float* __restrict__ bp2,
                                             float* __restrict__ out) {
  __shared__ float row[128];
  __shared__ float red[128];
  int g = blockIdx.x, t = threadIdx.x;
  row[t] = pooled[g * FD + t];
  __syncthreads();
  float acc = bp1[t];
#pragma unroll 8
  for (int k = 0; k < 128; k++) acc = fmaf(row[k], Wp1[k * FD + t], acc);
  acc = fmaxf(acc, 0.f);
  red[t] = acc * Wp2[t];
  __syncthreads();
  for (int st = 64; st > 0; st >>= 1) {
    if (t < st) red[t] += red[t + st];
    __syncthreads();
  }
  if (t == 0) out[g] = red[0] + bp2[0];
}

// ---------------- launch ----------------

extern "C" void kernel_launch(void* const* d_in, const int* in_sizes, int n_in,
                              void* d_out, int out_size, void* d_ws, size_t ws_size,
                              hipStream_t stream) {
  (void)in_sizes; (void)n_in; (void)out_size; (void)ws_size;

  const float* adj  = (const float*)d_in[0];
  const int*   edges= (const int*)d_in[1];
  const float* Wdec = (const float*)d_in[3];
  const float* bdec = (const float*)d_in[4];
  const float* Wc1  = (const float*)d_in[5];
  const float* bc1  = (const float*)d_in[6];
  const float* Wc2  = (const float*)d_in[7];
  const float* bc2  = (const float*)d_in[8];
  const float* Wp1  = (const float*)d_in[9];
  const float* bp1  = (const float*)d_in[10];
  const float* Wp2  = (const float*)d_in[11];
  const float* bp2  = (const float*)d_in[12];
  float* out = (float*)d_out;

  char* ws = (char*)d_ws;
  size_t off = 0;
  auto alloc = [&](size_t bytes) -> void* {
    void* p = ws + off;
    off += (bytes + 255) & ~(size_t)255;
    return p;
  };
  ushort* h16  = (ushort*)alloc((size_t)(NN + 1) * FD * 2);  // +1 zero row
  ushort* x1hi = (ushort*)alloc((size_t)NN * FD * 2);
  ushort* x1lo = (ushort*)alloc((size_t)NN * FD * 2);
  // hist | pooled | gbin contiguous -> single memset
  int*    hist = (int*)alloc((size_t)NN * 4);
  float*  pooled = (float*)alloc((size_t)NGRAPH * FD * 4);
  int*    gbin = (int*)alloc(256 * 4);
  int*    offs = (int*)alloc((size_t)NN * 4);
  int*    bsum = (int*)alloc(256 * 4);
  uint*   ec   = (uint*)alloc((size_t)NEP_MAX * 4);    // 8.1 MB padded records
  uint*   binbuf = (uint*)alloc((size_t)256 * BCAP * 4);  // 4.7 MB bucket bins
  float*  dinv = (float*)alloc((size_t)NN * 4);
  float*  wfused = (float*)alloc((size_t)KDEC * FD * 4);
  float*  bfused = (float*)alloc(FD * 4);
  ushort* wfh = (ushort*)alloc((size_t)KDEC * FD * 2);
  ushort* wfl = (ushort*)alloc((size_t)KDEC * FD * 2);
  ushort* w2h = (ushort*)alloc((size_t)FD * FD * 2);
  ushort* w2l = (ushort*)alloc((size_t)FD * FD * 2);

  hipMemsetAsync(hist, 0, (size_t)NN * 4 + (size_t)NGRAPH * FD * 4 + 256 * 4, stream);
  hipMemsetAsync(h16 + (size_t)NN * FD, 0, FD * 2, stream);  // zero row (dummy target)

  // histogram + radix-partition binning + ec dummy fill (one kernel, 1024 thr)
  k_histbin<<<256 + NEP_MAX / 4096, 1024, 0, stream>>>(edges, hist, ec, binbuf, gbin);
  // blocksum(padded) + Wfused=Wdec@Wc1 (+bfused) + prep(Wc2)
  k_misc1<<<448, 256, 0, stream>>>(hist, bsum, Wdec, Wc1, bdec, wfused, bfused,
                                   Wc2, w2h, w2l);
  // scanfinal(padded, scanb fused) + dinv(real) + prep(Wfused)
  k_misc2<<<384, 256, 0, stream>>>(hist, bsum, offs, dinv, wfused, wfh, wfl);
  // bucket -> exact CSR position (L2-local windows, no cross-XCD sharing)
  k_bscatter<<<256, 256, 0, stream>>>(binbuf, gbin, offs, ec);

  // t1 = dinv * (adj @ Wfused + bfused) -> bf16 table
  k_gemm<false><<<NN / 64, 256, 0, stream>>>(adj, nullptr, wfh, wfl, bfused, dinv, h16, KDEC);

  // x1 = relu(dinv*(sum t1 + t1_self) + bc1) -> hi/lo planes
  k_agg<0><<<NN / 4, 256, 0, stream>>>(h16, ec, offs, hist, dinv, bc1, x1hi, x1lo, nullptr);

  // t2 = dinv * (x1 @ Wc2) -> bf16 table
  k_gemm<true><<<NN / 64, 256, 0, stream>>>(x1hi, x1lo, w2h, w2l, nullptr, dinv, h16, FD);

  // pooled = segmax(relu(dinv*(sum t2 + t2_self) + bc2)) fused
  k_agg<1><<<NN / 4, 256, 0, stream>>>(h16, ec, offs, hist, dinv, bc2, nullptr, nullptr, pooled);

  // MLP head
  k_mlp<<<NGRAPH, 128, 0, stream>>>(pooled, Wp1, bp1, Wp2, bp2, out);
}

// Round 11
// 180.732 us; speedup vs baseline: 1.5297x; 1.2402x over previous
//
#include <hip/hip_runtime.h>
#include <hip/hip_fp16.h>
#include <cstdint>
#include <cstddef>

// Problem constants: B=256, C=1, NMAX=256 -> N=65536 nodes, E=N*16=1048576,
// EMB=HID=128, decode K = NMAX = 256.
#define NN   65536
#define NE   1048576
#define FD   128
#define KDEC 256
#define NGRAPH 256
// padded edge capacity: sum ceil(cnt/16)*16 <= NE + 15*NN
#define NEP_MAX (NE + 15 * NN)   // 2031616 records (= 4096 * 496)
#define DUMMY_SRC 65536u         // zero row index
#define EPB  4096                // edges per binning block
#define BCAP 4608                // per-bucket record capacity (mean 4096 + 8 sigma)

typedef __attribute__((ext_vector_type(8))) short s16x8;
typedef __attribute__((ext_vector_type(4))) float f32x4;

__device__ __forceinline__ ushort f2bf(float x) {
  uint u = __float_as_uint(x);
  uint r = (u + 0x7fffu + ((u >> 16) & 1u)) >> 16;  // RNE
  return (ushort)r;
}
__device__ __forceinline__ float bf2f(ushort h) {
  return __uint_as_float(((uint)h) << 16);
}

// ---------------- CSR build: radix-partition binning (NO global hist atomics) --
// blocks 0..255 (1024 thr): 4096 edges each. LDS bucket count -> scan ->
// LDS-sorted placement -> coalesced streamed write into per-bucket chunks.
// blocks 256..751: fill ec with dummy records (padding slots).

__global__ __launch_bounds__(1024) void k_histbin(const int* __restrict__ edges,
                                                  uint* __restrict__ ec,
                                                  uint* __restrict__ binbuf,
                                                  int* __restrict__ gbin) {
  const int b = blockIdx.x, t = threadIdx.x;
  if (b >= 256) {
    int fi = (b - 256) * 4096 + t * 4;  // 496 blocks * 4096 = NEP_MAX
    *(uint4*)(ec + fi) = make_uint4(DUMMY_SRC, DUMMY_SRC, DUMMY_SRC, DUMMY_SRC);
    return;
  }
  __shared__ int lcnt[256];
  __shared__ int lsum[256];   // inclusive prefix of lcnt
  __shared__ int gbase[256];
  __shared__ uint sorted[EPB];

  if (t < 256) lcnt[t] = 0;
  __syncthreads();

  uint rec[4];
  ushort bkt[4], lidx[4];
#pragma unroll
  for (int r = 0; r < 4; r++) {
    int i = b * EPB + r * 1024 + t;
    int2 e = ((const int2*)edges)[i];
    int bucket = e.y >> 8;
    int li = atomicAdd(&lcnt[bucket], 1);
    rec[r] = ((uint)bucket << 24) | ((uint)(e.y & 255) << 16) | (uint)e.x;
    bkt[r] = (ushort)bucket;
    lidx[r] = (ushort)li;
  }
  __syncthreads();

  // inclusive scan of lcnt -> lsum (first 256 threads; full-block barriers)
  if (t < 256) lsum[t] = lcnt[t];
  __syncthreads();
  for (int off = 1; off < 256; off <<= 1) {
    int v = 0;
    if (t < 256 && t >= off) v = lsum[t - off];
    __syncthreads();
    if (t < 256) lsum[t] += v;
    __syncthreads();
  }
  // reserve global bucket space (one atomic per bucket per block)
  if (t < 256) gbase[t] = atomicAdd(&gbin[t], lcnt[t]);
  __syncthreads();

  // place into LDS sorted buffer (exclusive base = lsum - lcnt)
#pragma unroll
  for (int r = 0; r < 4; r++) {
    int B = bkt[r];
    sorted[lsum[B] - lcnt[B] + lidx[r]] = rec[r];
  }
  __syncthreads();

  // stream out in slot order -> coalesced chunked stores
  for (int s = t; s < EPB; s += 1024) {
    uint v = sorted[s];
    int B = v >> 24;
    int ex = lsum[B] - lcnt[B];
    binbuf[B * BCAP + gbase[B] + (s - ex)] = v & 0xFFFFFFu;
  }
}

// phase 2: one block per bucket; sequential reads, writes confined to the
// bucket's contiguous ~27KB 64B-aligned CSR window (single writer, L2-local).
__global__ __launch_bounds__(256) void k_bscatter(const uint* __restrict__ binbuf,
                                                  const int* __restrict__ gbin,
                                                  const int* __restrict__ offs,
                                                  uint* __restrict__ ec) {
  __shared__ int cnt2[256];
  int b = blockIdx.x, t = threadIdx.x;
  cnt2[t] = 0;
  __syncthreads();
  int m = gbin[b];
  int nb = b << 8;
  for (int i = t; i < m; i += 256) {
    uint rec = binbuf[b * BCAP + i];
    int dlow = rec >> 16;
    int pos = offs[nb + dlow] + atomicAdd(&cnt2[dlow], 1);
    ec[pos] = rec & 0xFFFFu;
  }
}

// W pre-fragmentation helper (split bf16, fragment-major):
// dst(k,c) = ((k/32)*8 + c/16)*512 + ((c&15) + 16*((k&31)>>3))*8 + (k&7)
__device__ __forceinline__ void prep_one(const float* __restrict__ W,
                                         ushort* __restrict__ H,
                                         ushort* __restrict__ L, int i) {
  int k = i >> 7, c = i & 127;
  float w = W[i];
  ushort h = f2bf(w);
  ushort lo = f2bf(w - bf2f(h));
  size_t dst = ((size_t)((k >> 5) * 8 + (c >> 4)) * 64 +
                (size_t)((c & 15) + 16 * ((k & 31) >> 3))) * 8 + (k & 7);
  H[dst] = h;
  L[dst] = lo;
}

// misc1: blocks 0-255: bucket-local node histogram from binbuf (LDS counters,
//        zero global atomics) -> hist[] + padded blocksum bsum[b].
//        blocks 256-383: Wfused=Wdec@Wc1 (+bfused). blocks 384-447: prep Wc2.
__global__ __launch_bounds__(256) void k_misc1(const uint* __restrict__ binbuf,
                                               const int* __restrict__ gbin,
                                               int* __restrict__ hist,
                                               int* __restrict__ bsum,
                                               const float* __restrict__ Wdec,
                                               const float* __restrict__ Wc1,
                                               const float* __restrict__ bdec,
                                               float* __restrict__ wfused,
                                               float* __restrict__ bfused,
                                               const float* __restrict__ Wc2,
                                               ushort* __restrict__ w2h,
                                               ushort* __restrict__ w2l) {
  int b = blockIdx.x, t = threadIdx.x;
  if (b < 256) {
    __shared__ int lc[256];
    __shared__ int s[256];
    lc[t] = 0;
    __syncthreads();
    int m = gbin[b];
    for (int i = t; i < m; i += 256)
      atomicAdd(&lc[binbuf[b * BCAP + i] >> 16], 1);
    __syncthreads();
    hist[b * 256 + t] = lc[t];
    s[t] = (lc[t] + 15) & ~15;  // padded
    __syncthreads();
    for (int st = 128; st > 0; st >>= 1) {
      if (t < st) s[t] += s[t + st];
      __syncthreads();
    }
    if (t == 0) bsum[b] = s[0];
  } else if (b < 384) {
    int i = (b - 256) * 256 + t;  // 0..32767
    int k = i >> 7, c = i & 127;
    float acc = 0.f;
#pragma unroll 8
    for (int j = 0; j < 128; j++) acc = fmaf(Wdec[k * FD + j], Wc1[j * FD + c], acc);
    wfused[i] = acc;
    if (b == 256 && t < 128) {
      float ba = 0.f;
      for (int j = 0; j < 128; j++) ba = fmaf(bdec[j], Wc1[j * FD + t], ba);
      bfused[t] = ba;
    }
  } else {
    int i = (b - 384) * 256 + t;  // 0..16383
    prep_one(Wc2, w2h, w2l, i);
  }
}

// misc2: blocks 0-255 scanfinal over PADDED counts (scanb fused) + dinv(real) |
//        256-383 prep Wfused
__global__ __launch_bounds__(256) void k_misc2(const int* __restrict__ hist,
                                               const int* __restrict__ bsum,
                                               int* __restrict__ offs,
                                               float* __restrict__ dinv,
                                               const float* __restrict__ wfused,
                                               ushort* __restrict__ wfh,
                                               ushort* __restrict__ wfl) {
  int b = blockIdx.x, t = threadIdx.x;
  if (b < 256) {
    __shared__ int sb[256];
    __shared__ int s[256];
    sb[t] = bsum[t];
    int v = hist[b * 256 + t];
    int vp = (v + 15) & ~15;
    s[t] = vp;
    __syncthreads();
    for (int off = 1; off < 256; off <<= 1) {
      int addb = (t >= off) ? sb[t - off] : 0;
      int add = (t >= off) ? s[t - off] : 0;
      __syncthreads();
      sb[t] += addb;
      s[t] += add;
      __syncthreads();
    }
    int pb = (b > 0) ? sb[b - 1] : 0;
    offs[b * 256 + t] = pb + s[t] - vp;  // padded exclusive offsets
    dinv[b * 256 + t] = rsqrtf((float)(v + 1));
  } else {
    int i = (b - 256) * 256 + t;  // 0..32767
    prep_one(wfused, wfh, wfl, i);
  }
}

// ---------------- split-bf16 MFMA GEMM: Y[M,128] = X[M,K] @ W[K,128] (+bias) ----
// BM=64: 256 threads = 4 waves, wave = one 16-row m-frag. ASPLIT: A pre-split
// bf16 planes; else fp32 A. Output row-major bf16, row-scaled by scale[] if set
// (pre-scaled gather table t = dinv*h).

template <bool ASPLIT>
__global__ __launch_bounds__(256) void k_gemm(const void* __restrict__ A0,
                                              const void* __restrict__ A1,
                                              const ushort* __restrict__ Whi,
                                              const ushort* __restrict__ Wlo,
                                              const float* __restrict__ bias,
                                              const float* __restrict__ scale,
                                              ushort* __restrict__ Y, int K) {
  const int t = threadIdx.x;
  const int w = t >> 6;
  const int l = t & 63;
  const int lr = l & 15;   // row-in-frag (A) / col-in-frag (B,C)
  const int kg = l >> 4;   // k-group 0..3
  const int r0 = blockIdx.x * 64 + w * 16;

  f32x4 acc[8];
#pragma unroll
  for (int nb = 0; nb < 8; nb++) acc[nb] = (f32x4)0.f;

  for (int ks = 0; ks < K; ks += 32) {
    s16x8 ah, al;
    if (ASPLIT) {
      size_t base = (size_t)(r0 + lr) * K + ks + kg * 8;
      ah = *(const s16x8*)((const ushort*)A0 + base);
      al = *(const s16x8*)((const ushort*)A1 + base);
    } else {
      const float* xp = (const float*)A0 + (size_t)(r0 + lr) * K + ks + kg * 8;
      f32x4 x0 = *(const f32x4*)xp;
      f32x4 x1 = *(const f32x4*)(xp + 4);
      float xv[8] = {x0.x, x0.y, x0.z, x0.w, x1.x, x1.y, x1.z, x1.w};
      union { ushort u[8]; s16x8 v; } H, L;
#pragma unroll
      for (int e = 0; e < 8; e++) {
        ushort h = f2bf(xv[e]);
        H.u[e] = h;
        L.u[e] = f2bf(xv[e] - bf2f(h));
      }
      ah = H.v;
      al = L.v;
    }
    const size_t bbase = (size_t)(ks >> 5) * 4096 + (size_t)l * 8;
#pragma unroll
    for (int nb = 0; nb < 8; nb++) {
      s16x8 bh = *(const s16x8*)(Whi + bbase + nb * 512);
      s16x8 bl = *(const s16x8*)(Wlo + bbase + nb * 512);
      acc[nb] = __builtin_amdgcn_mfma_f32_16x16x32_bf16(ah, bh, acc[nb], 0, 0, 0);
      acc[nb] = __builtin_amdgcn_mfma_f32_16x16x32_bf16(ah, bl, acc[nb], 0, 0, 0);
      acc[nb] = __builtin_amdgcn_mfma_f32_16x16x32_bf16(al, bh, acc[nb], 0, 0, 0);
    }
  }

  // epilogue: C/D col = lr (within frag), row = kg*4 + reg
  float dvr[4];
#pragma unroll
  for (int r = 0; r < 4; r++)
    dvr[r] = scale ? scale[r0 + kg * 4 + r] : 1.f;

#pragma unroll
  for (int nb = 0; nb < 8; nb++) {
    int col = nb * 16 + lr;
    float bv = bias ? bias[col] : 0.f;
#pragma unroll
    for (int r = 0; r < 4; r++) {
      size_t row = (size_t)(r0 + kg * 4 + r);
      Y[row * FD + col] = f2bf((acc[nb][r] + bv) * dvr[r]);
    }
  }
}

// ---------------- GCN aggregation: wave-per-node, UNIFORM 8-deep pipeline ------
// Table t = dinv*h, bf16 [NN+1][128] (row NN = zeros, dummy-pad target).
// Wave = 1 node; lane l: edge parity half=l>>5, dims dl=(l&31)*4 (ushort4).
// Segments padded to multiples of 16 -> single uniform loop, 8 gathers in
// flight per lane-half for EVERY node, zero remainder/divergence.
// out[d] = relu( dinv[d]*(sum_e t[src_e] + t[d]) + b )
// EMIT=0: write hi/lo bf16 planes. EMIT=1: fused segment-max pooling.

template <int EMIT>
__global__ __launch_bounds__(256) void k_agg(const ushort* __restrict__ h16,
                                             const uint* __restrict__ ec,
                                             const int* __restrict__ offs,
                                             const int* __restrict__ hist,
                                             const float* __restrict__ dinv,
                                             const float* __restrict__ bias,
                                             ushort* __restrict__ yhi,
                                             ushort* __restrict__ ylo,
                                             float* __restrict__ pooled) {
  __shared__ int pmax[128];
  const int t = threadIdx.x;
  if (EMIT == 1) {
    if (t < 128) pmax[t] = 0;
    __syncthreads();
  }
  const int n = blockIdx.x * 4 + (t >> 6);
  const int l = t & 63;
  const int half = l >> 5;
  const int dl = (l & 31) * 4;

  const int cnt_p = (hist[n] + 15) & ~15;  // padded count
  const uint* ep = ec + offs[n];

  float a0 = 0.f, a1 = 0.f, a2 = 0.f, a3 = 0.f;
  float b0 = 0.f, b1 = 0.f, b2 = 0.f, b3 = 0.f;
  for (int i = half; i < cnt_p; i += 16) {
    uint s0 = ep[i];
    uint s1 = ep[i + 2];
    uint s2 = ep[i + 4];
    uint s3 = ep[i + 6];
    uint s4 = ep[i + 8];
    uint s5 = ep[i + 10];
    uint s6 = ep[i + 12];
    uint s7 = ep[i + 14];
    ushort4 v0 = *(const ushort4*)(h16 + ((size_t)s0 << 7) + dl);
    ushort4 v1 = *(const ushort4*)(h16 + ((size_t)s1 << 7) + dl);
    ushort4 v2 = *(const ushort4*)(h16 + ((size_t)s2 << 7) + dl);
    ushort4 v3 = *(const ushort4*)(h16 + ((size_t)s3 << 7) + dl);
    ushort4 v4 = *(const ushort4*)(h16 + ((size_t)s4 << 7) + dl);
    ushort4 v5 = *(const ushort4*)(h16 + ((size_t)s5 << 7) + dl);
    ushort4 v6 = *(const ushort4*)(h16 + ((size_t)s6 << 7) + dl);
    ushort4 v7 = *(const ushort4*)(h16 + ((size_t)s7 << 7) + dl);
    a0 += bf2f(v0.x); a1 += bf2f(v0.y); a2 += bf2f(v0.z); a3 += bf2f(v0.w);
    b0 += bf2f(v1.x); b1 += bf2f(v1.y); b2 += bf2f(v1.z); b3 += bf2f(v1.w);
    a0 += bf2f(v2.x); a1 += bf2f(v2.y); a2 += bf2f(v2.z); a3 += bf2f(v2.w);
    b0 += bf2f(v3.x); b1 += bf2f(v3.y); b2 += bf2f(v3.z); b3 += bf2f(v3.w);
    a0 += bf2f(v4.x); a1 += bf2f(v4.y); a2 += bf2f(v4.z); a3 += bf2f(v4.w);
    b0 += bf2f(v5.x); b1 += bf2f(v5.y); b2 += bf2f(v5.z); b3 += bf2f(v5.w);
    a0 += bf2f(v6.x); a1 += bf2f(v6.y); a2 += bf2f(v6.z); a3 += bf2f(v6.w);
    b0 += bf2f(v7.x); b1 += bf2f(v7.y); b2 += bf2f(v7.z); b3 += bf2f(v7.w);
  }
  a0 += b0; a1 += b1; a2 += b2; a3 += b3;
  a0 += __shfl_xor(a0, 32);
  a1 += __shfl_xor(a1, 32);
  a2 += __shfl_xor(a2, 32);
  a3 += __shfl_xor(a3, 32);

  if (l < 32) {
    float dv = dinv[n];
    ushort4 vs = *(const ushort4*)(h16 + ((size_t)n << 7) + dl);  // t[d]
    float4 bb = *(const float4*)(bias + dl);
    float o0 = fmaxf(fmaf(dv, a0 + bf2f(vs.x), bb.x), 0.f);
    float o1 = fmaxf(fmaf(dv, a1 + bf2f(vs.y), bb.y), 0.f);
    float o2 = fmaxf(fmaf(dv, a2 + bf2f(vs.z), bb.z), 0.f);
    float o3 = fmaxf(fmaf(dv, a3 + bf2f(vs.w), bb.w), 0.f);
    if (EMIT == 0) {
      ushort4 hi, lo;
      hi.x = f2bf(o0); lo.x = f2bf(o0 - bf2f(hi.x));
      hi.y = f2bf(o1); lo.y = f2bf(o1 - bf2f(hi.y));
      hi.z = f2bf(o2); lo.z = f2bf(o2 - bf2f(hi.z));
      hi.w = f2bf(o3); lo.w = f2bf(o3 - bf2f(hi.w));
      size_t base = (size_t)n * FD + dl;
      *(ushort4*)(yhi + base) = hi;
      *(ushort4*)(ylo + base) = lo;
    } else {
      // relu>=0: int-compare == float-compare for non-negative floats
      atomicMax(&pmax[dl + 0], __float_as_int(o0));
      atomicMax(&pmax[dl + 1], __float_as_int(o1));
      atomicMax(&pmax[dl + 2], __float_as_int(o2));
      atomicMax(&pmax[dl + 3], __float_as_int(o3));
    }
  }
  if (EMIT == 1) {
    __syncthreads();
    if (t < 128) {
      int gr = blockIdx.x >> 6;  // 64 blocks (256 nodes) per graph
      atomicMax((int*)pooled + gr * FD + t, pmax[t]);
    }
  }
}

// ---------------- MLP head ----------------

__global__ __launch_bounds__(128) void k_mlp(const float* __restrict__ pooled,
                                             const float* __restrict__ Wp1,
                                             const float* __restrict__ bp1,
                                             const float* __restrict__ Wp2,
                                             const float* __restrict__ bp2,
                                             float* __restrict__ out) {
  __shared__ float row[128];
  __shared__ float red[128];
  int g = blockIdx.x, t = threadIdx.x;
  row[t] = pooled[g * FD + t];
  __syncthreads();
  float acc = bp1[t];
#pragma unroll 8
  for (int k = 0; k < 128; k++) acc = fmaf(row[k], Wp1[k * FD + t], acc);
  acc = fmaxf(acc, 0.f);
  red[t] = acc * Wp2[t];
  __syncthreads();
  for (int st = 64; st > 0; st >>= 1) {
    if (t < st) red[t] += red[t + st];
    __syncthreads();
  }
  if (t == 0) out[g] = red[0] + bp2[0];
}

// ---------------- launch ----------------

extern "C" void kernel_launch(void* const* d_in, const int* in_sizes, int n_in,
                              void* d_out, int out_size, void* d_ws, size_t ws_size,
                              hipStream_t stream) {
  (void)in_sizes; (void)n_in; (void)out_size; (void)ws_size;

  const float* adj  = (const float*)d_in[0];
  const int*   edges= (const int*)d_in[1];
  const float* Wdec = (const float*)d_in[3];
  const float* bdec = (const float*)d_in[4];
  const float* Wc1  = (const float*)d_in[5];
  const float* bc1  = (const float*)d_in[6];
  const float* Wc2  = (const float*)d_in[7];
  const float* bc2  = (const float*)d_in[8];
  const float* Wp1  = (const float*)d_in[9];
  const float* bp1  = (const float*)d_in[10];
  const float* Wp2  = (const float*)d_in[11];
  const float* bp2  = (const float*)d_in[12];
  float* out = (float*)d_out;

  char* ws = (char*)d_ws;
  size_t off = 0;
  auto alloc = [&](size_t bytes) -> void* {
    void* p = ws + off;
    off += (bytes + 255) & ~(size_t)255;
    return p;
  };
  ushort* h16  = (ushort*)alloc((size_t)(NN + 1) * FD * 2);  // +1 zero row
  ushort* x1hi = (ushort*)alloc((size_t)NN * FD * 2);
  ushort* x1lo = (ushort*)alloc((size_t)NN * FD * 2);
  // pooled | gbin contiguous -> single memset (hist needs no memset now)
  float*  pooled = (float*)alloc((size_t)NGRAPH * FD * 4);
  int*    gbin = (int*)alloc(256 * 4);
  int*    hist = (int*)alloc((size_t)NN * 4);
  int*    offs = (int*)alloc((size_t)NN * 4);
  int*    bsum = (int*)alloc(256 * 4);
  uint*   ec   = (uint*)alloc((size_t)NEP_MAX * 4);    // 8.1 MB padded records
  uint*   binbuf = (uint*)alloc((size_t)256 * BCAP * 4);  // 4.7 MB bucket bins
  float*  dinv = (float*)alloc((size_t)NN * 4);
  float*  wfused = (float*)alloc((size_t)KDEC * FD * 4);
  float*  bfused = (float*)alloc(FD * 4);
  ushort* wfh = (ushort*)alloc((size_t)KDEC * FD * 2);
  ushort* wfl = (ushort*)alloc((size_t)KDEC * FD * 2);
  ushort* w2h = (ushort*)alloc((size_t)FD * FD * 2);
  ushort* w2l = (ushort*)alloc((size_t)FD * FD * 2);

  hipMemsetAsync(pooled, 0, (size_t)NGRAPH * FD * 4 + 256 * 4, stream);
  hipMemsetAsync(h16 + (size_t)NN * FD, 0, FD * 2, stream);  // zero row (dummy target)

  // radix-partition binning + ec dummy fill (no global hist atomics)
  k_histbin<<<256 + NEP_MAX / 4096, 1024, 0, stream>>>(edges, ec, binbuf, gbin);
  // bucket-hist (LDS-local) -> hist + padded bsum | Wfused (+bfused) | prep Wc2
  k_misc1<<<448, 256, 0, stream>>>(binbuf, gbin, hist, bsum, Wdec, Wc1, bdec,
                                   wfused, bfused, Wc2, w2h, w2l);
  // scanfinal(padded, scanb fused) + dinv(real) + prep(Wfused)
  k_misc2<<<384, 256, 0, stream>>>(hist, bsum, offs, dinv, wfused, wfh, wfl);
  // bucket -> exact CSR position (L2-local windows, no cross-XCD sharing)
  k_bscatter<<<256, 256, 0, stream>>>(binbuf, gbin, offs, ec);

  // t1 = dinv * (adj @ Wfused + bfused) -> bf16 table
  k_gemm<false><<<NN / 64, 256, 0, stream>>>(adj, nullptr, wfh, wfl, bfused, dinv, h16, KDEC);

  // x1 = relu(dinv*(sum t1 + t1_self) + bc1) -> hi/lo planes
  k_agg<0><<<NN / 4, 256, 0, stream>>>(h16, ec, offs, hist, dinv, bc1, x1hi, x1lo, nullptr);

  // t2 = dinv * (x1 @ Wc2) -> bf16 table
  k_gemm<true><<<NN / 64, 256, 0, stream>>>(x1hi, x1lo, w2h, w2l, nullptr, dinv, h16, FD);

  // pooled = segmax(relu(dinv*(sum t2 + t2_self) + bc2)) fused
  k_agg<1><<<NN / 4, 256, 0, stream>>>(h16, ec, offs, hist, dinv, bc2, nullptr, nullptr, pooled);

  // MLP head
  k_mlp<<<NGRAPH, 128, 0, stream>>>(pooled, Wp1, bp1, Wp2, bp2, out);
}

// Round 12
// 168.282 us; speedup vs baseline: 1.6429x; 1.0740x over previous
//
#include <hip/hip_runtime.h>
#include <hip/hip_fp16.h>
#include <cstdint>
#include <cstddef>

// Problem constants: B=256, C=1, NMAX=256 -> N=65536 nodes, E=N*16=1048576,
// EMB=HID=128, decode K = NMAX = 256.
#define NN   65536
#define NE   1048576
#define FD   128
#define KDEC 256
#define NGRAPH 256
// padded edge capacity: sum ceil(cnt/16)*16 <= NE + 15*NN
#define NEP_MAX (NE + 15 * NN)   // 2031616 records (= 4096 * 496)
#define DUMMY_SRC 65536u         // zero row index
#define EPB  4096                // edges per binning block
#define BCAP 4608                // per-bucket record capacity (mean 4096 + 8 sigma)

typedef __attribute__((ext_vector_type(8))) short s16x8;
typedef __attribute__((ext_vector_type(4))) float f32x4;

__device__ __forceinline__ ushort f2bf(float x) {
  uint u = __float_as_uint(x);
  uint r = (u + 0x7fffu + ((u >> 16) & 1u)) >> 16;  // RNE
  return (ushort)r;
}
__device__ __forceinline__ float bf2f(ushort h) {
  return __uint_as_float(((uint)h) << 16);
}

// ---------------- CSR build: radix-partition binning (NO global hist atomics) --

__global__ __launch_bounds__(1024) void k_histbin(const int* __restrict__ edges,
                                                  uint* __restrict__ ec,
                                                  uint* __restrict__ binbuf,
                                                  int* __restrict__ gbin) {
  const int b = blockIdx.x, t = threadIdx.x;
  if (b >= 256) {
    int fi = (b - 256) * 4096 + t * 4;  // 496 blocks * 4096 = NEP_MAX
    *(uint4*)(ec + fi) = make_uint4(DUMMY_SRC, DUMMY_SRC, DUMMY_SRC, DUMMY_SRC);
    return;
  }
  __shared__ int lcnt[256];
  __shared__ int lsum[256];   // inclusive prefix of lcnt
  __shared__ int gbase[256];
  __shared__ uint sorted[EPB];

  if (t < 256) lcnt[t] = 0;
  __syncthreads();

  uint rec[4];
  ushort bkt[4], lidx[4];
#pragma unroll
  for (int r = 0; r < 4; r++) {
    int i = b * EPB + r * 1024 + t;
    int2 e = ((const int2*)edges)[i];
    int bucket = e.y >> 8;
    int li = atomicAdd(&lcnt[bucket], 1);
    rec[r] = ((uint)bucket << 24) | ((uint)(e.y & 255) << 16) | (uint)e.x;
    bkt[r] = (ushort)bucket;
    lidx[r] = (ushort)li;
  }
  __syncthreads();

  if (t < 256) lsum[t] = lcnt[t];
  __syncthreads();
  for (int off = 1; off < 256; off <<= 1) {
    int v = 0;
    if (t < 256 && t >= off) v = lsum[t - off];
    __syncthreads();
    if (t < 256) lsum[t] += v;
    __syncthreads();
  }
  if (t < 256) gbase[t] = atomicAdd(&gbin[t], lcnt[t]);
  __syncthreads();

#pragma unroll
  for (int r = 0; r < 4; r++) {
    int B = bkt[r];
    sorted[lsum[B] - lcnt[B] + lidx[r]] = rec[r];
  }
  __syncthreads();

  for (int s = t; s < EPB; s += 1024) {
    uint v = sorted[s];
    int B = v >> 24;
    int ex = lsum[B] - lcnt[B];
    binbuf[B * BCAP + gbase[B] + (s - ex)] = v & 0xFFFFFFu;
  }
}

// phase 2: one block per bucket; sequential reads, writes confined to the
// bucket's contiguous ~27KB 64B-aligned CSR window (single writer, L2-local).
__global__ __launch_bounds__(256) void k_bscatter(const uint* __restrict__ binbuf,
                                                  const int* __restrict__ gbin,
                                                  const int* __restrict__ offs,
                                                  uint* __restrict__ ec) {
  __shared__ int cnt2[256];
  int b = blockIdx.x, t = threadIdx.x;
  cnt2[t] = 0;
  __syncthreads();
  int m = gbin[b];
  int nb = b << 8;
  for (int i = t; i < m; i += 256) {
    uint rec = binbuf[b * BCAP + i];
    int dlow = rec >> 16;
    int pos = offs[nb + dlow] + atomicAdd(&cnt2[dlow], 1);
    ec[pos] = rec & 0xFFFFu;
  }
}

// W pre-fragmentation helper (split bf16, fragment-major):
// dst(k,c) = ((k/32)*8 + c/16)*512 + ((c&15) + 16*((k&31)>>3))*8 + (k&7)
__device__ __forceinline__ void prep_one(const float* __restrict__ W,
                                         ushort* __restrict__ H,
                                         ushort* __restrict__ L, int i) {
  int k = i >> 7, c = i & 127;
  float w = W[i];
  ushort h = f2bf(w);
  ushort lo = f2bf(w - bf2f(h));
  size_t dst = ((size_t)((k >> 5) * 8 + (c >> 4)) * 64 +
                (size_t)((c & 15) + 16 * ((k & 31) >> 3))) * 8 + (k & 7);
  H[dst] = h;
  L[dst] = lo;
}

// misc1: blocks 0-255: bucket-local node histogram (LDS counters) -> hist +
//        padded bsum[b]. 256-383: Wfused (+bfused). 384-447: prep Wc2.
__global__ __launch_bounds__(256) void k_misc1(const uint* __restrict__ binbuf,
                                               const int* __restrict__ gbin,
                                               int* __restrict__ hist,
                                               int* __restrict__ bsum,
                                               const float* __restrict__ Wdec,
                                               const float* __restrict__ Wc1,
                                               const float* __restrict__ bdec,
                                               float* __restrict__ wfused,
                                               float* __restrict__ bfused,
                                               const float* __restrict__ Wc2,
                                               ushort* __restrict__ w2h,
                                               ushort* __restrict__ w2l) {
  int b = blockIdx.x, t = threadIdx.x;
  if (b < 256) {
    __shared__ int lc[256];
    __shared__ int s[256];
    lc[t] = 0;
    __syncthreads();
    int m = gbin[b];
    for (int i = t; i < m; i += 256)
      atomicAdd(&lc[binbuf[b * BCAP + i] >> 16], 1);
    __syncthreads();
    hist[b * 256 + t] = lc[t];
    s[t] = (lc[t] + 15) & ~15;  // padded
    __syncthreads();
    for (int st = 128; st > 0; st >>= 1) {
      if (t < st) s[t] += s[t + st];
      __syncthreads();
    }
    if (t == 0) bsum[b] = s[0];
  } else if (b < 384) {
    int i = (b - 256) * 256 + t;  // 0..32767
    int k = i >> 7, c = i & 127;
    float acc = 0.f;
#pragma unroll 8
    for (int j = 0; j < 128; j++) acc = fmaf(Wdec[k * FD + j], Wc1[j * FD + c], acc);
    wfused[i] = acc;
    if (b == 256 && t < 128) {
      float ba = 0.f;
      for (int j = 0; j < 128; j++) ba = fmaf(bdec[j], Wc1[j * FD + t], ba);
      bfused[t] = ba;
    }
  } else {
    int i = (b - 384) * 256 + t;  // 0..16383
    prep_one(Wc2, w2h, w2l, i);
  }
}

// misc2: blocks 0-255 scanfinal over PADDED counts (scanb fused) + dinv(real) |
//        256-383 prep Wfused
__global__ __launch_bounds__(256) void k_misc2(const int* __restrict__ hist,
                                               const int* __restrict__ bsum,
                                               int* __restrict__ offs,
                                               float* __restrict__ dinv,
                                               const float* __restrict__ wfused,
                                               ushort* __restrict__ wfh,
                                               ushort* __restrict__ wfl) {
  int b = blockIdx.x, t = threadIdx.x;
  if (b < 256) {
    __shared__ int sb[256];
    __shared__ int s[256];
    sb[t] = bsum[t];
    int v = hist[b * 256 + t];
    int vp = (v + 15) & ~15;
    s[t] = vp;
    __syncthreads();
    for (int off = 1; off < 256; off <<= 1) {
      int addb = (t >= off) ? sb[t - off] : 0;
      int add = (t >= off) ? s[t - off] : 0;
      __syncthreads();
      sb[t] += addb;
      s[t] += add;
      __syncthreads();
    }
    int pb = (b > 0) ? sb[b - 1] : 0;
    offs[b * 256 + t] = pb + s[t] - vp;  // padded exclusive offsets
    dinv[b * 256 + t] = rsqrtf((float)(v + 1));
  } else {
    int i = (b - 256) * 256 + t;  // 0..32767
    prep_one(wfused, wfh, wfl, i);
  }
}

// ---------------- split-bf16 MFMA GEMM, LDS-B double-buffered pipeline ----------
// 256 threads = 4 waves; wave owns 32 rows (2 m-frags); BM=128, grid=M/128.
// B (hi+lo, 16 KB per K-step) staged cooperatively into double-buffered LDS —
// loaded ONCE per block per step instead of once per wave (8x L2 traffic cut).
// A prefetched one K-step ahead into registers (split deferred to use-time).
// Output row-major bf16, row-scaled by scale[] if set (t = dinv*h).

template <bool ASPLIT>
__global__ __launch_bounds__(256) void k_gemm(const void* __restrict__ A0,
                                              const void* __restrict__ A1,
                                              const ushort* __restrict__ Whi,
                                              const ushort* __restrict__ Wlo,
                                              const float* __restrict__ bias,
                                              const float* __restrict__ scale,
                                              ushort* __restrict__ Y, int K) {
  __shared__ ushort Bs[2][8192];  // [buf][hi 4096 | lo 4096] = 32 KB
  const int t = threadIdx.x;
  const int w = t >> 6;
  const int l = t & 63;
  const int lr = l & 15;   // row-in-frag (A) / col-in-frag (B,C)
  const int kg = l >> 4;   // k-group 0..3
  const int r0 = blockIdx.x * 128 + w * 32;
  const int nks = K >> 5;

  f32x4 acc[2][8];
#pragma unroll
  for (int mb = 0; mb < 2; mb++)
#pragma unroll
    for (int nb = 0; nb < 8; nb++) acc[mb][nb] = (f32x4)0.f;

  // prefetch state (raw A regs; split at use-time so loads issue early)
  f32x4 araw[4];
  s16x8 ahn[2], aln[2];
  s16x8 bh0, bh1, bl0, bl1;

  auto issueA = [&](int s) {
#pragma unroll
    for (int mb = 0; mb < 2; mb++) {
      size_t base = (size_t)(r0 + mb * 16 + lr) * K + s * 32 + kg * 8;
      if (ASPLIT) {
        ahn[mb] = *(const s16x8*)((const ushort*)A0 + base);
        aln[mb] = *(const s16x8*)((const ushort*)A1 + base);
      } else {
        const float* xp = (const float*)A0 + base;
        araw[mb * 2] = *(const f32x4*)xp;
        araw[mb * 2 + 1] = *(const f32x4*)(xp + 4);
      }
    }
  };
  auto issueB = [&](int s) {
    const ushort* ph = Whi + (size_t)s * 4096 + t * 16;
    const ushort* pl = Wlo + (size_t)s * 4096 + t * 16;
    bh0 = *(const s16x8*)ph;
    bh1 = *(const s16x8*)(ph + 8);
    bl0 = *(const s16x8*)pl;
    bl1 = *(const s16x8*)(pl + 8);
  };
  auto writeB = [&](int buf) {
    *(s16x8*)&Bs[buf][t * 16] = bh0;
    *(s16x8*)&Bs[buf][t * 16 + 8] = bh1;
    *(s16x8*)&Bs[buf][4096 + t * 16] = bl0;
    *(s16x8*)&Bs[buf][4096 + t * 16 + 8] = bl1;
  };

  issueB(0);
  issueA(0);
  writeB(0);
  __syncthreads();

  int buf = 0;
  for (int s = 0; s < nks; ++s) {
    // materialize current A fragments (loads issued one iteration ago)
    s16x8 ah[2], al[2];
    if (ASPLIT) {
      ah[0] = ahn[0]; ah[1] = ahn[1];
      al[0] = aln[0]; al[1] = aln[1];
    } else {
#pragma unroll
      for (int mb = 0; mb < 2; mb++) {
        float xv[8] = {araw[mb*2].x, araw[mb*2].y, araw[mb*2].z, araw[mb*2].w,
                       araw[mb*2+1].x, araw[mb*2+1].y, araw[mb*2+1].z, araw[mb*2+1].w};
        union { ushort u[8]; s16x8 v; } H, L;
#pragma unroll
        for (int e = 0; e < 8; e++) {
          ushort h = f2bf(xv[e]);
          H.u[e] = h;
          L.u[e] = f2bf(xv[e] - bf2f(h));
        }
        ah[mb] = H.v;
        al[mb] = L.v;
      }
    }
    const bool more = (s + 1 < nks);
    if (more) { issueB(s + 1); issueA(s + 1); }  // in flight during compute

    // compute from LDS buf (48 MFMA per wave per step)
#pragma unroll
    for (int nb = 0; nb < 8; nb++) {
      s16x8 bh = *(const s16x8*)&Bs[buf][nb * 512 + l * 8];
      s16x8 bl = *(const s16x8*)&Bs[buf][4096 + nb * 512 + l * 8];
#pragma unroll
      for (int mb = 0; mb < 2; mb++) {
        acc[mb][nb] = __builtin_amdgcn_mfma_f32_16x16x32_bf16(ah[mb], bh, acc[mb][nb], 0, 0, 0);
        acc[mb][nb] = __builtin_amdgcn_mfma_f32_16x16x32_bf16(ah[mb], bl, acc[mb][nb], 0, 0, 0);
        acc[mb][nb] = __builtin_amdgcn_mfma_f32_16x16x32_bf16(al[mb], bh, acc[mb][nb], 0, 0, 0);
      }
    }
    if (more) {
      writeB(buf ^ 1);   // waits on issueB loads (covered by compute above)
      __syncthreads();   // buf^1 visible; all waves done reading buf
      buf ^= 1;
    }
  }

  // epilogue: C/D col = lr (within frag), row = kg*4 + reg
  float dvr[2][4];
#pragma unroll
  for (int mb = 0; mb < 2; mb++)
#pragma unroll
    for (int r = 0; r < 4; r++)
      dvr[mb][r] = scale ? scale[r0 + mb * 16 + kg * 4 + r] : 1.f;

#pragma unroll
  for (int nb = 0; nb < 8; nb++) {
    int col = nb * 16 + lr;
    float bv = bias ? bias[col] : 0.f;
#pragma unroll
    for (int mb = 0; mb < 2; mb++)
#pragma unroll
      for (int r = 0; r < 4; r++) {
        size_t row = (size_t)(r0 + mb * 16 + kg * 4 + r);
        Y[row * FD + col] = f2bf((acc[mb][nb][r] + bv) * dvr[mb][r]);
      }
  }
}

// ---------------- GCN aggregation: wave-per-node, UNIFORM 8-deep pipeline ------
// Table t = dinv*h, bf16 [NN+1][128] (row NN = zeros, dummy-pad target).
// out[d] = relu( dinv[d]*(sum_e t[src_e] + t[d]) + b )
// EMIT=0: write hi/lo bf16 planes. EMIT=1: fused segment-max pooling.

template <int EMIT>
__global__ __launch_bounds__(256) void k_agg(const ushort* __restrict__ h16,
                                             const uint* __restrict__ ec,
                                             const int* __restrict__ offs,
                                             const int* __restrict__ hist,
                                             const float* __restrict__ dinv,
                                             const float* __restrict__ bias,
                                             ushort* __restrict__ yhi,
                                             ushort* __restrict__ ylo,
                                             float* __restrict__ pooled) {
  __shared__ int pmax[128];
  const int t = threadIdx.x;
  if (EMIT == 1) {
    if (t < 128) pmax[t] = 0;
    __syncthreads();
  }
  const int n = blockIdx.x * 4 + (t >> 6);
  const int l = t & 63;
  const int half = l >> 5;
  const int dl = (l & 31) * 4;

  const int cnt_p = (hist[n] + 15) & ~15;  // padded count
  const uint* ep = ec + offs[n];

  float a0 = 0.f, a1 = 0.f, a2 = 0.f, a3 = 0.f;
  float b0 = 0.f, b1 = 0.f, b2 = 0.f, b3 = 0.f;
  for (int i = half; i < cnt_p; i += 16) {
    uint s0 = ep[i];
    uint s1 = ep[i + 2];
    uint s2 = ep[i + 4];
    uint s3 = ep[i + 6];
    uint s4 = ep[i + 8];
    uint s5 = ep[i + 10];
    uint s6 = ep[i + 12];
    uint s7 = ep[i + 14];
    ushort4 v0 = *(const ushort4*)(h16 + ((size_t)s0 << 7) + dl);
    ushort4 v1 = *(const ushort4*)(h16 + ((size_t)s1 << 7) + dl);
    ushort4 v2 = *(const ushort4*)(h16 + ((size_t)s2 << 7) + dl);
    ushort4 v3 = *(const ushort4*)(h16 + ((size_t)s3 << 7) + dl);
    ushort4 v4 = *(const ushort4*)(h16 + ((size_t)s4 << 7) + dl);
    ushort4 v5 = *(const ushort4*)(h16 + ((size_t)s5 << 7) + dl);
    ushort4 v6 = *(const ushort4*)(h16 + ((size_t)s6 << 7) + dl);
    ushort4 v7 = *(const ushort4*)(h16 + ((size_t)s7 << 7) + dl);
    a0 += bf2f(v0.x); a1 += bf2f(v0.y); a2 += bf2f(v0.z); a3 += bf2f(v0.w);
    b0 += bf2f(v1.x); b1 += bf2f(v1.y); b2 += bf2f(v1.z); b3 += bf2f(v1.w);
    a0 += bf2f(v2.x); a1 += bf2f(v2.y); a2 += bf2f(v2.z); a3 += bf2f(v2.w);
    b0 += bf2f(v3.x); b1 += bf2f(v3.y); b2 += bf2f(v3.z); b3 += bf2f(v3.w);
    a0 += bf2f(v4.x); a1 += bf2f(v4.y); a2 += bf2f(v4.z); a3 += bf2f(v4.w);
    b0 += bf2f(v5.x); b1 += bf2f(v5.y); b2 += bf2f(v5.z); b3 += bf2f(v5.w);
    a0 += bf2f(v6.x); a1 += bf2f(v6.y); a2 += bf2f(v6.z); a3 += bf2f(v6.w);
    b0 += bf2f(v7.x); b1 += bf2f(v7.y); b2 += bf2f(v7.z); b3 += bf2f(v7.w);
  }
  a0 += b0; a1 += b1; a2 += b2; a3 += b3;
  a0 += __shfl_xor(a0, 32);
  a1 += __shfl_xor(a1, 32);
  a2 += __shfl_xor(a2, 32);
  a3 += __shfl_xor(a3, 32);

  if (l < 32) {
    float dv = dinv[n];
    ushort4 vs = *(const ushort4*)(h16 + ((size_t)n << 7) + dl);  // t[d]
    float4 bb = *(const float4*)(bias + dl);
    float o0 = fmaxf(fmaf(dv, a0 + bf2f(vs.x), bb.x), 0.f);
    float o1 = fmaxf(fmaf(dv, a1 + bf2f(vs.y), bb.y), 0.f);
    float o2 = fmaxf(fmaf(dv, a2 + bf2f(vs.z), bb.z), 0.f);
    float o3 = fmaxf(fmaf(dv, a3 + bf2f(vs.w), bb.w), 0.f);
    if (EMIT == 0) {
      ushort4 hi, lo;
      hi.x = f2bf(o0); lo.x = f2bf(o0 - bf2f(hi.x));
      hi.y = f2bf(o1); lo.y = f2bf(o1 - bf2f(hi.y));
      hi.z = f2bf(o2); lo.z = f2bf(o2 - bf2f(hi.z));
      hi.w = f2bf(o3); lo.w = f2bf(o3 - bf2f(hi.w));
      size_t base = (size_t)n * FD + dl;
      *(ushort4*)(yhi + base) = hi;
      *(ushort4*)(ylo + base) = lo;
    } else {
      // relu>=0: int-compare == float-compare for non-negative floats
      atomicMax(&pmax[dl + 0], __float_as_int(o0));
      atomicMax(&pmax[dl + 1], __float_as_int(o1));
      atomicMax(&pmax[dl + 2], __float_as_int(o2));
      atomicMax(&pmax[dl + 3], __float_as_int(o3));
    }
  }
  if (EMIT == 1) {
    __syncthreads();
    if (t < 128) {
      int gr = blockIdx.x >> 6;  // 64 blocks (256 nodes) per graph
      atomicMax((int*)pooled + gr * FD + t, pmax[t]);
    }
  }
}

// ---------------- MLP head ----------------

__global__ __launch_bounds__(128) void k_mlp(const float* __restrict__ pooled,
                                             const float* __restrict__ Wp1,
                                             const float* __restrict__ bp1,
                                             const float* __restrict__ Wp2,
                                             const float* __restrict__ bp2,
                                             float* __restrict__ out) {
  __shared__ float row[128];
  __shared__ float red[128];
  int g = blockIdx.x, t = threadIdx.x;
  row[t] = pooled[g * FD + t];
  __syncthreads();
  float acc = bp1[t];
#pragma unroll 8
  for (int k = 0; k < 128; k++) acc = fmaf(row[k], Wp1[k * FD + t], acc);
  acc = fmaxf(acc, 0.f);
  red[t] = acc * Wp2[t];
  __syncthreads();
  for (int st = 64; st > 0; st >>= 1) {
    if (t < st) red[t] += red[t + st];
    __syncthreads();
  }
  if (t == 0) out[g] = red[0] + bp2[0];
}

// ---------------- launch ----------------

extern "C" void kernel_launch(void* const* d_in, const int* in_sizes, int n_in,
                              void* d_out, int out_size, void* d_ws, size_t ws_size,
                              hipStream_t stream) {
  (void)in_sizes; (void)n_in; (void)out_size; (void)ws_size;

  const float* adj  = (const float*)d_in[0];
  const int*   edges= (const int*)d_in[1];
  const float* Wdec = (const float*)d_in[3];
  const float* bdec = (const float*)d_in[4];
  const float* Wc1  = (const float*)d_in[5];
  const float* bc1  = (const float*)d_in[6];
  const float* Wc2  = (const float*)d_in[7];
  const float* bc2  = (const float*)d_in[8];
  const float* Wp1  = (const float*)d_in[9];
  const float* bp1  = (const float*)d_in[10];
  const float* Wp2  = (const float*)d_in[11];
  const float* bp2  = (const float*)d_in[12];
  float* out = (float*)d_out;

  char* ws = (char*)d_ws;
  size_t off = 0;
  auto alloc = [&](size_t bytes) -> void* {
    void* p = ws + off;
    off += (bytes + 255) & ~(size_t)255;
    return p;
  };
  ushort* h16  = (ushort*)alloc((size_t)(NN + 1) * FD * 2);  // +1 zero row
  ushort* x1hi = (ushort*)alloc((size_t)NN * FD * 2);
  ushort* x1lo = (ushort*)alloc((size_t)NN * FD * 2);
  // pooled | gbin contiguous -> single memset (hist needs no memset now)
  float*  pooled = (float*)alloc((size_t)NGRAPH * FD * 4);
  int*    gbin = (int*)alloc(256 * 4);
  int*    hist = (int*)alloc((size_t)NN * 4);
  int*    offs = (int*)alloc((size_t)NN * 4);
  int*    bsum = (int*)alloc(256 * 4);
  uint*   ec   = (uint*)alloc((size_t)NEP_MAX * 4);    // 8.1 MB padded records
  uint*   binbuf = (uint*)alloc((size_t)256 * BCAP * 4);  // 4.7 MB bucket bins
  float*  dinv = (float*)alloc((size_t)NN * 4);
  float*  wfused = (float*)alloc((size_t)KDEC * FD * 4);
  float*  bfused = (float*)alloc(FD * 4);
  ushort* wfh = (ushort*)alloc((size_t)KDEC * FD * 2);
  ushort* wfl = (ushort*)alloc((size_t)KDEC * FD * 2);
  ushort* w2h = (ushort*)alloc((size_t)FD * FD * 2);
  ushort* w2l = (ushort*)alloc((size_t)FD * FD * 2);

  hipMemsetAsync(pooled, 0, (size_t)NGRAPH * FD * 4 + 256 * 4, stream);
  hipMemsetAsync(h16 + (size_t)NN * FD, 0, FD * 2, stream);  // zero row (dummy target)

  // radix-partition binning + ec dummy fill (no global hist atomics)
  k_histbin<<<256 + NEP_MAX / 4096, 1024, 0, stream>>>(edges, ec, binbuf, gbin);
  // bucket-hist (LDS-local) -> hist + padded bsum | Wfused (+bfused) | prep Wc2
  k_misc1<<<448, 256, 0, stream>>>(binbuf, gbin, hist, bsum, Wdec, Wc1, bdec,
                                   wfused, bfused, Wc2, w2h, w2l);
  // scanfinal(padded, scanb fused) + dinv(real) + prep(Wfused)
  k_misc2<<<384, 256, 0, stream>>>(hist, bsum, offs, dinv, wfused, wfh, wfl);
  // bucket -> exact CSR position (L2-local windows, no cross-XCD sharing)
  k_bscatter<<<256, 256, 0, stream>>>(binbuf, gbin, offs, ec);

  // t1 = dinv * (adj @ Wfused + bfused) -> bf16 table
  k_gemm<false><<<NN / 128, 256, 0, stream>>>(adj, nullptr, wfh, wfl, bfused, dinv, h16, KDEC);

  // x1 = relu(dinv*(sum t1 + t1_self) + bc1) -> hi/lo planes
  k_agg<0><<<NN / 4, 256, 0, stream>>>(h16, ec, offs, hist, dinv, bc1, x1hi, x1lo, nullptr);

  // t2 = dinv * (x1 @ Wc2) -> bf16 table
  k_gemm<true><<<NN / 128, 256, 0, stream>>>(x1hi, x1lo, w2h, w2l, nullptr, dinv, h16, FD);

  // pooled = segmax(relu(dinv*(sum t2 + t2_self) + bc2)) fused
  k_agg<1><<<NN / 4, 256, 0, stream>>>(h16, ec, offs, hist, dinv, bc2, nullptr, nullptr, pooled);

  // MLP head
  k_mlp<<<NGRAPH, 128, 0, stream>>>(pooled, Wp1, bp1, Wp2, bp2, out);
}